// Round 1
// baseline (472.146 us; speedup 1.0000x reference)
//
#include <hip/hip_runtime.h>
#include <math.h>

// Problem constants
#define LSEQ   4096
#define DHALF  256
#define NSTATE 8

__device__ __forceinline__ float silu_f(float v)     { return v / (1.0f + __expf(-v)); }
__device__ __forceinline__ float softplus_f(float v) { return v > 20.0f ? v : log1pf(__expf(v)); }

// ============================================================================
// GEMM A (in_proj): C[m=(b,l)][e] = sum_k hs[m][k] * W[e][k]
// M=8192, N=1024, K=512. Epilogue scatters into direction-adjusted layout:
//   e<256           -> x_t[b][l][e]
//   256<=e<512      -> z_t[b][l][e-256]
//   512<=e<768      -> x_t[b+2][4095-l][e-512]   (backward stream, reversed)
//   768<=e<1024     -> z_t[b+2][4095-l][e-768]
// x_t/z_t layout: [4][4096][256] (channel-fastest)
// ============================================================================
__global__ __launch_bounds__(256)
void k_in_proj(const float* __restrict__ A, const float* __restrict__ B,
               float* __restrict__ x_t, float* __restrict__ z_t)
{
    __shared__ float As[16][132];
    __shared__ float Bs[16][132];
    const int t  = threadIdx.x;
    const int bx = blockIdx.x;      // col block 0..7
    const int by = blockIdx.y;      // row block 0..63
    const int lrow = t >> 1;
    const int lk0  = (t & 1) * 8;
    const int tx = t & 15, ty = t >> 4;
    float acc[8][8];
#pragma unroll
    for (int i = 0; i < 8; ++i)
#pragma unroll
        for (int j = 0; j < 8; ++j) acc[i][j] = 0.0f;

    const float* Ap = A + ((size_t)(by * 128 + lrow)) * 512 + lk0;
    const float* Bp = B + ((size_t)(bx * 128 + lrow)) * 512 + lk0;

    for (int kb = 0; kb < 512; kb += 16) {
        float4 a0 = *(const float4*)(Ap + kb);
        float4 a1 = *(const float4*)(Ap + kb + 4);
        float4 b0 = *(const float4*)(Bp + kb);
        float4 b1 = *(const float4*)(Bp + kb + 4);
        __syncthreads();
        As[lk0+0][lrow] = a0.x; As[lk0+1][lrow] = a0.y;
        As[lk0+2][lrow] = a0.z; As[lk0+3][lrow] = a0.w;
        As[lk0+4][lrow] = a1.x; As[lk0+5][lrow] = a1.y;
        As[lk0+6][lrow] = a1.z; As[lk0+7][lrow] = a1.w;
        Bs[lk0+0][lrow] = b0.x; Bs[lk0+1][lrow] = b0.y;
        Bs[lk0+2][lrow] = b0.z; Bs[lk0+3][lrow] = b0.w;
        Bs[lk0+4][lrow] = b1.x; Bs[lk0+5][lrow] = b1.y;
        Bs[lk0+6][lrow] = b1.z; Bs[lk0+7][lrow] = b1.w;
        __syncthreads();
#pragma unroll
        for (int k = 0; k < 16; ++k) {
            float4 av0 = *(const float4*)&As[k][ty*8];
            float4 av1 = *(const float4*)&As[k][ty*8+4];
            float4 bv0 = *(const float4*)&Bs[k][tx*8];
            float4 bv1 = *(const float4*)&Bs[k][tx*8+4];
            float av[8] = {av0.x,av0.y,av0.z,av0.w,av1.x,av1.y,av1.z,av1.w};
            float bv[8] = {bv0.x,bv0.y,bv0.z,bv0.w,bv1.x,bv1.y,bv1.z,bv1.w};
#pragma unroll
            for (int i = 0; i < 8; ++i)
#pragma unroll
                for (int j = 0; j < 8; ++j)
                    acc[i][j] = fmaf(av[i], bv[j], acc[i][j]);
        }
    }

    const int e0     = bx * 128 + tx * 8;
    const int region = e0 >> 8;        // 0..3, constant across the 8-col group
    const int eo     = e0 & 255;
#pragma unroll
    for (int i = 0; i < 8; ++i) {
        int m = by * 128 + ty * 8 + i;
        int b = m >> 12, l = m & 4095;
        float* dst;
        if (region == 0)      dst = x_t + ((size_t)b * 4096 + l) * 256 + eo;
        else if (region == 1) dst = z_t + ((size_t)b * 4096 + l) * 256 + eo;
        else if (region == 2) dst = x_t + ((size_t)(b + 2) * 4096 + (4095 - l)) * 256 + eo;
        else                  dst = z_t + ((size_t)(b + 2) * 4096 + (4095 - l)) * 256 + eo;
        *(float4*)(dst)     = make_float4(acc[i][0], acc[i][1], acc[i][2], acc[i][3]);
        *(float4*)(dst + 4) = make_float4(acc[i][4], acc[i][5], acc[i][6], acc[i][7]);
    }
}

// ============================================================================
// GEMM F (out_proj): out[b][l][o] = sum_c Ybuf[b][l][c] * W[o][c]
// M=8192, N=512, K=1024. Plain row-major output.
// ============================================================================
__global__ __launch_bounds__(256)
void k_out_proj(const float* __restrict__ A, const float* __restrict__ B,
                float* __restrict__ out)
{
    __shared__ float As[16][132];
    __shared__ float Bs[16][132];
    const int t  = threadIdx.x;
    const int bx = blockIdx.x;      // col block 0..3
    const int by = blockIdx.y;      // row block 0..63
    const int lrow = t >> 1;
    const int lk0  = (t & 1) * 8;
    const int tx = t & 15, ty = t >> 4;
    float acc[8][8];
#pragma unroll
    for (int i = 0; i < 8; ++i)
#pragma unroll
        for (int j = 0; j < 8; ++j) acc[i][j] = 0.0f;

    const float* Ap = A + ((size_t)(by * 128 + lrow)) * 1024 + lk0;
    const float* Bp = B + ((size_t)(bx * 128 + lrow)) * 1024 + lk0;

    for (int kb = 0; kb < 1024; kb += 16) {
        float4 a0 = *(const float4*)(Ap + kb);
        float4 a1 = *(const float4*)(Ap + kb + 4);
        float4 b0 = *(const float4*)(Bp + kb);
        float4 b1 = *(const float4*)(Bp + kb + 4);
        __syncthreads();
        As[lk0+0][lrow] = a0.x; As[lk0+1][lrow] = a0.y;
        As[lk0+2][lrow] = a0.z; As[lk0+3][lrow] = a0.w;
        As[lk0+4][lrow] = a1.x; As[lk0+5][lrow] = a1.y;
        As[lk0+6][lrow] = a1.z; As[lk0+7][lrow] = a1.w;
        Bs[lk0+0][lrow] = b0.x; Bs[lk0+1][lrow] = b0.y;
        Bs[lk0+2][lrow] = b0.z; Bs[lk0+3][lrow] = b0.w;
        Bs[lk0+4][lrow] = b1.x; Bs[lk0+5][lrow] = b1.y;
        Bs[lk0+6][lrow] = b1.z; Bs[lk0+7][lrow] = b1.w;
        __syncthreads();
#pragma unroll
        for (int k = 0; k < 16; ++k) {
            float4 av0 = *(const float4*)&As[k][ty*8];
            float4 av1 = *(const float4*)&As[k][ty*8+4];
            float4 bv0 = *(const float4*)&Bs[k][tx*8];
            float4 bv1 = *(const float4*)&Bs[k][tx*8+4];
            float av[8] = {av0.x,av0.y,av0.z,av0.w,av1.x,av1.y,av1.z,av1.w};
            float bv[8] = {bv0.x,bv0.y,bv0.z,bv0.w,bv1.x,bv1.y,bv1.z,bv1.w};
#pragma unroll
            for (int i = 0; i < 8; ++i)
#pragma unroll
                for (int j = 0; j < 8; ++j)
                    acc[i][j] = fmaf(av[i], bv[j], acc[i][j]);
        }
    }
#pragma unroll
    for (int i = 0; i < 8; ++i) {
        size_t m = (size_t)(by * 128 + ty * 8 + i);
        float* dst = out + m * 512 + bx * 128 + tx * 8;
        *(float4*)(dst)     = make_float4(acc[i][0], acc[i][1], acc[i][2], acc[i][3]);
        *(float4*)(dst + 4) = make_float4(acc[i][4], acc[i][5], acc[i][6], acc[i][7]);
    }
}

// ============================================================================
// conv_x: dilated (8) causal depthwise conv + SiLU.  x_t -> u_t, both [4][4096][256]
// taps: w3*x[l] + w2*x[l-8] + w1*x[l-16] + w0*x[l-24]
// ============================================================================
__global__ __launch_bounds__(256)
void k_conv_x(const float* __restrict__ x_t, const float* __restrict__ w,
              float* __restrict__ u_t)
{
    const int bid = blockIdx.x;             // 0..16383
    const int b = bid >> 12, l = bid & 4095;
    const int d = threadIdx.x;
    const float* base = x_t + (size_t)b * 4096 * 256 + d;
    const float w0 = w[d*4+0], w1 = w[d*4+1], w2 = w[d*4+2], w3 = w[d*4+3];
    float acc = w3 * base[(size_t)l * 256];
    if (l >= 8)  acc += w2 * base[(size_t)(l - 8)  * 256];
    if (l >= 16) acc += w1 * base[(size_t)(l - 16) * 256];
    if (l >= 24) acc += w0 * base[(size_t)(l - 24) * 256];
    u_t[((size_t)b * 4096 + l) * 256 + d] = silu_f(acc);
}

// ============================================================================
// conv_z: dilation-1 causal depthwise conv + SiLU.  z_t -> Ybuf z-channels,
// with the final direction un-reversal folded in.
// Ybuf layout: [2][4096][1024]; fwd z -> ch 256+d; bwd z -> ch 768+d at 4095-l
// ============================================================================
__global__ __launch_bounds__(256)
void k_conv_z(const float* __restrict__ z_t, const float* __restrict__ w,
              float* __restrict__ ybuf)
{
    const int bid = blockIdx.x;
    const int b = bid >> 12, l = bid & 4095;
    const int d = threadIdx.x;
    const float* base = z_t + (size_t)b * 4096 * 256 + d;
    const float w0 = w[d*4+0], w1 = w[d*4+1], w2 = w[d*4+2], w3 = w[d*4+3];
    float acc = w3 * base[(size_t)l * 256];
    if (l >= 1) acc += w2 * base[(size_t)(l - 1) * 256];
    if (l >= 2) acc += w1 * base[(size_t)(l - 2) * 256];
    if (l >= 3) acc += w0 * base[(size_t)(l - 3) * 256];
    float v = silu_f(acc);
    if (b < 2) ybuf[((size_t)b * 4096 + l) * 1024 + 256 + d] = v;
    else       ybuf[((size_t)(b - 2) * 4096 + (4095 - l)) * 1024 + 768 + d] = v;
}

// ============================================================================
// x_proj: xdbl[m=(b,l)][e] = sum_d u_t[m][d] * Wx[e][d];  M=16384, N=48, K=256
// xdbl layout: [4][4096][48]  (cols 0..31 dtr, 32..39 B, 40..47 C)
// ============================================================================
__global__ __launch_bounds__(256)
void k_xproj(const float* __restrict__ U, const float* __restrict__ W,
             float* __restrict__ xdbl)
{
    __shared__ float As[32][132];
    __shared__ float Bs[32][52];
    const int t = threadIdx.x;
    const int m0 = blockIdx.x * 128;        // 0..127 blocks
    const int lrow = t >> 1;
    const int lk0  = (t & 1) * 16;
    const int tx = t & 15, ty = t >> 4;
    const int be = t >> 2;                  // 0..63 (guard <48)
    const int bk = (t & 3) * 8;
    float acc[8][3];
#pragma unroll
    for (int i = 0; i < 8; ++i) { acc[i][0] = 0.f; acc[i][1] = 0.f; acc[i][2] = 0.f; }

    for (int kb = 0; kb < 256; kb += 32) {
        const float* ap = U + ((size_t)(m0 + lrow)) * 256 + kb + lk0;
        float4 a0 = *(const float4*)(ap);
        float4 a1 = *(const float4*)(ap + 4);
        float4 a2 = *(const float4*)(ap + 8);
        float4 a3 = *(const float4*)(ap + 12);
        float4 b0, b1;
        if (be < 48) {
            const float* bp = W + (size_t)be * 256 + kb + bk;
            b0 = *(const float4*)(bp);
            b1 = *(const float4*)(bp + 4);
        }
        __syncthreads();
        As[lk0+ 0][lrow] = a0.x; As[lk0+ 1][lrow] = a0.y; As[lk0+ 2][lrow] = a0.z; As[lk0+ 3][lrow] = a0.w;
        As[lk0+ 4][lrow] = a1.x; As[lk0+ 5][lrow] = a1.y; As[lk0+ 6][lrow] = a1.z; As[lk0+ 7][lrow] = a1.w;
        As[lk0+ 8][lrow] = a2.x; As[lk0+ 9][lrow] = a2.y; As[lk0+10][lrow] = a2.z; As[lk0+11][lrow] = a2.w;
        As[lk0+12][lrow] = a3.x; As[lk0+13][lrow] = a3.y; As[lk0+14][lrow] = a3.z; As[lk0+15][lrow] = a3.w;
        if (be < 48) {
            Bs[bk+0][be] = b0.x; Bs[bk+1][be] = b0.y; Bs[bk+2][be] = b0.z; Bs[bk+3][be] = b0.w;
            Bs[bk+4][be] = b1.x; Bs[bk+5][be] = b1.y; Bs[bk+6][be] = b1.z; Bs[bk+7][be] = b1.w;
        }
        __syncthreads();
#pragma unroll
        for (int k = 0; k < 32; ++k) {
            float4 av0 = *(const float4*)&As[k][ty*8];
            float4 av1 = *(const float4*)&As[k][ty*8+4];
            float av[8] = {av0.x,av0.y,av0.z,av0.w,av1.x,av1.y,av1.z,av1.w};
            float bva = Bs[k][tx*3+0];
            float bvb = Bs[k][tx*3+1];
            float bvc = Bs[k][tx*3+2];
#pragma unroll
            for (int i = 0; i < 8; ++i) {
                acc[i][0] = fmaf(av[i], bva, acc[i][0]);
                acc[i][1] = fmaf(av[i], bvb, acc[i][1]);
                acc[i][2] = fmaf(av[i], bvc, acc[i][2]);
            }
        }
    }
#pragma unroll
    for (int i = 0; i < 8; ++i) {
        size_t row = (size_t)(m0 + ty * 8 + i) * 48 + tx * 3;
        xdbl[row + 0] = acc[i][0];
        xdbl[row + 1] = acc[i][1];
        xdbl[row + 2] = acc[i][2];
    }
}

// ============================================================================
// dt_proj + softplus: delta[m=(b,l)][d] = softplus(sum_r Wdt[d][r]*xdbl[m][r] + bdt[d])
// M=16384, N=256, K=32 (single K block)
// ============================================================================
__global__ __launch_bounds__(256)
void k_dtproj(const float* __restrict__ xdbl, const float* __restrict__ Wdt,
              const float* __restrict__ bdt, float* __restrict__ delta_t)
{
    __shared__ float As[32][68];
    __shared__ float Bs[32][132];
    const int t  = threadIdx.x;
    const int m0 = blockIdx.x * 64;         // 0..255
    const int n0 = blockIdx.y * 128;        // 0..1
    const int ai = t >> 2, ak = (t & 3) * 8;
    const int be = t >> 1, bk = (t & 1) * 16;
    {
        const float* ap = xdbl + (size_t)(m0 + ai) * 48 + ak;
        float4 a0 = *(const float4*)(ap);
        float4 a1 = *(const float4*)(ap + 4);
        const float* bp = Wdt + (size_t)(n0 + be) * 32 + bk;
        float4 b0 = *(const float4*)(bp);
        float4 b1 = *(const float4*)(bp + 4);
        float4 b2 = *(const float4*)(bp + 8);
        float4 b3 = *(const float4*)(bp + 12);
        As[ak+0][ai] = a0.x; As[ak+1][ai] = a0.y; As[ak+2][ai] = a0.z; As[ak+3][ai] = a0.w;
        As[ak+4][ai] = a1.x; As[ak+5][ai] = a1.y; As[ak+6][ai] = a1.z; As[ak+7][ai] = a1.w;
        Bs[bk+ 0][be] = b0.x; Bs[bk+ 1][be] = b0.y; Bs[bk+ 2][be] = b0.z; Bs[bk+ 3][be] = b0.w;
        Bs[bk+ 4][be] = b1.x; Bs[bk+ 5][be] = b1.y; Bs[bk+ 6][be] = b1.z; Bs[bk+ 7][be] = b1.w;
        Bs[bk+ 8][be] = b2.x; Bs[bk+ 9][be] = b2.y; Bs[bk+10][be] = b2.z; Bs[bk+11][be] = b2.w;
        Bs[bk+12][be] = b3.x; Bs[bk+13][be] = b3.y; Bs[bk+14][be] = b3.z; Bs[bk+15][be] = b3.w;
    }
    __syncthreads();
    const int tx = t & 15, ty = t >> 4;     // cols tx*8, rows ty*4
    float acc[4][8];
#pragma unroll
    for (int i = 0; i < 4; ++i)
#pragma unroll
        for (int j = 0; j < 8; ++j) acc[i][j] = 0.0f;
#pragma unroll
    for (int k = 0; k < 32; ++k) {
        float4 a4  = *(const float4*)&As[k][ty*4];
        float4 bv0 = *(const float4*)&Bs[k][tx*8];
        float4 bv1 = *(const float4*)&Bs[k][tx*8+4];
        float av[4] = {a4.x, a4.y, a4.z, a4.w};
        float bv[8] = {bv0.x,bv0.y,bv0.z,bv0.w,bv1.x,bv1.y,bv1.z,bv1.w};
#pragma unroll
        for (int i = 0; i < 4; ++i)
#pragma unroll
            for (int j = 0; j < 8; ++j)
                acc[i][j] = fmaf(av[i], bv[j], acc[i][j]);
    }
    float bias[8];
#pragma unroll
    for (int j = 0; j < 8; ++j) bias[j] = bdt[n0 + tx*8 + j];
#pragma unroll
    for (int i = 0; i < 4; ++i) {
        size_t m = (size_t)(m0 + ty * 4 + i);
        float4 o0, o1;
        o0.x = softplus_f(acc[i][0] + bias[0]);
        o0.y = softplus_f(acc[i][1] + bias[1]);
        o0.z = softplus_f(acc[i][2] + bias[2]);
        o0.w = softplus_f(acc[i][3] + bias[3]);
        o1.x = softplus_f(acc[i][4] + bias[4]);
        o1.y = softplus_f(acc[i][5] + bias[5]);
        o1.z = softplus_f(acc[i][6] + bias[6]);
        o1.w = softplus_f(acc[i][7] + bias[7]);
        float* dst = delta_t + m * 256 + n0 + tx * 8;
        *(float4*)(dst)     = o0;
        *(float4*)(dst + 4) = o1;
    }
}

// ============================================================================
// Selective scan, chunked (64 chunks x 64 steps).
// h[n] <- exp(delta*A[d][n])*h[n] + delta*u*B[n];  y = sum_n h[n]*C[n] + u*D[d]
// Pass 1: per (b,d,chunk): S = sum delta, Bc[n] = local scan from 0.
// Pass 2: per (b,d,n): sequential over chunks: hinit[c]=h; h = exp(a*S_c)*h + Bc.
// Pass 3: replay chunk with h0 = hinit, emit y into Ybuf (direction-mapped).
// ============================================================================
__global__ __launch_bounds__(256)
void k_scan1(const float* __restrict__ delta_t, const float* __restrict__ u_t,
             const float* __restrict__ xdbl, const float* __restrict__ A_log,
             float* __restrict__ chS, float* __restrict__ chB)
{
    __shared__ float Bsh[8][64];
    const int b = blockIdx.x >> 6;
    const int c = blockIdx.x & 63;
    const int d = threadIdx.x;
    const int l0 = c * 64;
    for (int s = threadIdx.x; s < 512; s += 256) {
        int i = s >> 3, n = s & 7;
        Bsh[n][i] = xdbl[((size_t)b * 4096 + l0 + i) * 48 + 32 + n];
    }
    float a[8];
#pragma unroll
    for (int n = 0; n < 8; ++n) a[n] = -__expf(A_log[d * 8 + n]);
    float h[8];
#pragma unroll
    for (int n = 0; n < 8; ++n) h[n] = 0.0f;
    float S = 0.0f;
    __syncthreads();
    const float* dp = delta_t + ((size_t)b * 4096 + l0) * 256 + d;
    const float* up = u_t     + ((size_t)b * 4096 + l0) * 256 + d;
    for (int i = 0; i < 64; ++i) {
        float dlt = dp[(size_t)i * 256];
        float u   = up[(size_t)i * 256];
        float du  = dlt * u;
        S += dlt;
#pragma unroll
        for (int n = 0; n < 8; ++n) {
            float dA = __expf(dlt * a[n]);
            h[n] = dA * h[n] + du * Bsh[n][i];
        }
    }
    chS[((size_t)b * 64 + c) * 256 + d] = S;
#pragma unroll
    for (int n = 0; n < 8; ++n)
        chB[(((size_t)b * 64 + c) * 8 + n) * 256 + d] = h[n];
}

__global__ __launch_bounds__(256)
void k_scan2(const float* __restrict__ chS, const float* __restrict__ chB,
             const float* __restrict__ A_log, float* __restrict__ hinit)
{
    const int b = blockIdx.x >> 3;
    const int n = blockIdx.x & 7;
    const int d = threadIdx.x;
    const float a = -__expf(A_log[d * 8 + n]);
    float h = 0.0f;
    for (int c = 0; c < 64; ++c) {
        size_t idx = (((size_t)b * 64 + c) * 8 + n) * 256 + d;
        hinit[idx] = h;
        float S = chS[((size_t)b * 64 + c) * 256 + d];
        h = __expf(a * S) * h + chB[idx];
    }
}

__global__ __launch_bounds__(256)
void k_scan3(const float* __restrict__ delta_t, const float* __restrict__ u_t,
             const float* __restrict__ xdbl, const float* __restrict__ A_log,
             const float* __restrict__ Dp, const float* __restrict__ hinit,
             float* __restrict__ ybuf)
{
    __shared__ float Bsh[8][64];
    __shared__ float Csh[8][64];
    const int b = blockIdx.x >> 6;
    const int c = blockIdx.x & 63;
    const int d = threadIdx.x;
    const int l0 = c * 64;
    for (int s = threadIdx.x; s < 512; s += 256) {
        int i = s >> 3, n = s & 7;
        size_t row = ((size_t)b * 4096 + l0 + i) * 48;
        Bsh[n][i] = xdbl[row + 32 + n];
        Csh[n][i] = xdbl[row + 40 + n];
    }
    float a[8], h[8];
#pragma unroll
    for (int n = 0; n < 8; ++n) {
        a[n] = -__expf(A_log[d * 8 + n]);
        h[n] = hinit[(((size_t)b * 64 + c) * 8 + n) * 256 + d];
    }
    const float Dd = Dp[d];
    __syncthreads();
    const float* dp = delta_t + ((size_t)b * 4096 + l0) * 256 + d;
    const float* up = u_t     + ((size_t)b * 4096 + l0) * 256 + d;
    for (int i = 0; i < 64; ++i) {
        float dlt = dp[(size_t)i * 256];
        float u   = up[(size_t)i * 256];
        float du  = dlt * u;
        float y   = u * Dd;
#pragma unroll
        for (int n = 0; n < 8; ++n) {
            float dA = __expf(dlt * a[n]);
            h[n] = dA * h[n] + du * Bsh[n][i];
            y += h[n] * Csh[n][i];
        }
        int l = l0 + i;
        if (b < 2) ybuf[((size_t)b * 4096 + l) * 1024 + d] = y;
        else       ybuf[((size_t)(b - 2) * 4096 + (4095 - l)) * 1024 + 512 + d] = y;
    }
}

// ============================================================================
extern "C" void kernel_launch(void* const* d_in, const int* in_sizes, int n_in,
                              void* d_out, int out_size, void* d_ws, size_t ws_size,
                              hipStream_t stream)
{
    const float* hs    = (const float*)d_in[0];   // (2,4096,512)
    const float* w_in  = (const float*)d_in[1];   // (1024,512)
    const float* w_xp  = (const float*)d_in[2];   // (48,256)
    const float* w_dt  = (const float*)d_in[3];   // (256,32)
    const float* b_dt  = (const float*)d_in[4];   // (256,)
    const float* A_log = (const float*)d_in[5];   // (256,8)
    const float* Dpar  = (const float*)d_in[6];   // (256,)
    const float* w_cx  = (const float*)d_in[7];   // (256,1,4)
    const float* w_cz  = (const float*)d_in[8];   // (256,1,4)
    const float* w_out = (const float*)d_in[9];   // (512,1024)
    float* out = (float*)d_out;                   // (2,4096,512)

    float* ws = (float*)d_ws;
    const size_t NX = (size_t)4 * 4096 * 256;     // 4194304
    float* x_t  = ws;                             // [4][4096][256]
    float* z_t  = ws + NX;                        // [4][4096][256]
    float* u_t  = ws + 2 * NX;                    // [4][4096][256]
    float* ybuf = ws + 3 * NX;                    // [2][4096][1024] = 8388608
    float* xdbl = ws + 3 * NX + 8388608;          // [4][4096][48]   = 786432
    float* dlt  = xdbl + 786432;                  // [4][4096][256]  = NX
    float* chS  = dlt + NX;                       // [4][64][256]    = 65536
    float* chB  = chS + 65536;                    // [4][64][8][256] = 524288
    float* hin  = chB + 524288;                   // [4][64][8][256] = 524288

    k_in_proj <<<dim3(8, 64),  256, 0, stream>>>(hs, w_in, x_t, z_t);
    k_conv_x  <<<16384,        256, 0, stream>>>(x_t, w_cx, u_t);
    k_conv_z  <<<16384,        256, 0, stream>>>(z_t, w_cz, ybuf);
    k_xproj   <<<128,          256, 0, stream>>>(u_t, w_xp, xdbl);
    k_dtproj  <<<dim3(256, 2), 256, 0, stream>>>(xdbl, w_dt, b_dt, dlt);
    k_scan1   <<<256,          256, 0, stream>>>(dlt, u_t, xdbl, A_log, chS, chB);
    k_scan2   <<<32,           256, 0, stream>>>(chS, chB, A_log, hin);
    k_scan3   <<<256,          256, 0, stream>>>(dlt, u_t, xdbl, A_log, Dpar, hin, ybuf);
    k_out_proj<<<dim3(4, 64),  256, 0, stream>>>(ybuf, w_out, out);
}

// Round 2
// 310.392 us; speedup vs baseline: 1.5211x; 1.5211x over previous
//
#include <hip/hip_runtime.h>
#include <math.h>

// Problem constants
#define LSEQ   4096
#define DHALF  256
#define NSTATE 8
#define NCHUNK 128           // scan chunks
#define CLEN   32            // chunk length (NCHUNK*CLEN = 4096)

typedef __attribute__((ext_vector_type(8))) short short8;   // 8 x bf16 fragment (guide-verified)
typedef __attribute__((ext_vector_type(4))) float f32x4;
typedef __attribute__((ext_vector_type(4))) unsigned short us4;

__device__ __forceinline__ float silu_f(float v)     { return v / (1.0f + __expf(-v)); }
__device__ __forceinline__ float softplus_f(float v) { return v > 20.0f ? v : log1pf(__expf(v)); }

__device__ __forceinline__ unsigned short f2bf(float f) {
    unsigned int u = __float_as_uint(f);
    return (unsigned short)((u + 0x7fffu + ((u >> 16) & 1u)) >> 16);
}
__device__ __forceinline__ float bf2f(unsigned short h) {
    return __uint_as_float(((unsigned int)h) << 16);
}

// async global->LDS, 16B per lane; LDS dest = wave-uniform base + lane*16
__device__ __forceinline__ void gload16(const void* g, void* l) {
    __builtin_amdgcn_global_load_lds((const __attribute__((address_space(1))) void*)g,
                                     (__attribute__((address_space(3))) void*)l, 16, 0, 0);
}

// ============================================================================
// fp32 -> bf16 hi/lo split cast.  n4 = element_count/4
// ============================================================================
__global__ __launch_bounds__(256)
void k_cast_hilo(const float* __restrict__ src, unsigned short* __restrict__ hi,
                 unsigned short* __restrict__ lo, int n4)
{
    int i = blockIdx.x * 256 + threadIdx.x;
    if (i >= n4) return;
    float4 v = ((const float4*)src)[i];
    us4 h, l;
    h.x = f2bf(v.x); l.x = f2bf(v.x - bf2f(h.x));
    h.y = f2bf(v.y); l.y = f2bf(v.y - bf2f(h.y));
    h.z = f2bf(v.z); l.z = f2bf(v.z - bf2f(h.z));
    h.w = f2bf(v.w); l.w = f2bf(v.w - bf2f(h.w));
    ((us4*)hi)[i] = h;
    ((us4*)lo)[i] = l;
}

// ============================================================================
// MFMA bt-GEMM core (C = A * B^T), bf16 hi/lo split (3 products, ~fp32 precision).
// A: [M][K] bf16 hi/lo, B: [N][K] bf16 hi/lo, both K-contiguous.
// 128x128 tile / block, 4 waves each computing 64x64 via 4x4 16x16x32 MFMAs.
// LDS: per tile 128 rows x 32 bf16, chunked in 16B units with XOR swizzle:
//   chunk (r, c) stored at row position p = c ^ ((r>>1)&3)  -> 2-way bank alias (free).
// Staging: swizzle applied on the per-lane GLOBAL address (LDS dst must stay
// wave-uniform base + lane*16 per the global_load_lds constraint).
// ============================================================================
#define GEMM_CORE(K_)                                                                   \
    const int t = threadIdx.x;                                                          \
    const int wv = t >> 6, lane = t & 63;                                               \
    const int wm = (wv & 1) * 64, wn = (wv >> 1) * 64;                                  \
    const int lm = lane & 15, q = lane >> 4;                                            \
    const int M0 = blockIdx.y * 128, N0 = blockIdx.x * 128;                             \
    const int r1 = wv * 32 + (lane >> 2);                                               \
    const int r2 = r1 + 16;                                                             \
    const int slot = lane & 3;                                                          \
    const int c1 = slot ^ ((r1 >> 1) & 3);                                              \
    const int c2 = slot ^ ((r2 >> 1) & 3);                                              \
    const int lb1 = wv * 32 * 32;            /* ushort idx, wave-uniform */             \
    const int lb2 = lb1 + 16 * 32;                                                      \
    const int pq = (q ^ ((lm >> 1) & 3)) * 8;                                           \
    const size_t ga1 = (size_t)(M0 + r1) * K_ + c1 * 8;                                 \
    const size_t ga2 = (size_t)(M0 + r2) * K_ + c2 * 8;                                 \
    const size_t gb1 = (size_t)(N0 + r1) * K_ + c1 * 8;                                 \
    const size_t gb2 = (size_t)(N0 + r2) * K_ + c2 * 8;                                 \
    f32x4 acc[4][4] = {};                                                               \
    for (int kb = 0; kb < K_; kb += 32) {                                               \
        __syncthreads();                                                                \
        gload16(Ah + ga1 + kb, &sAh[lb1]);                                              \
        gload16(Ah + ga2 + kb, &sAh[lb2]);                                              \
        gload16(Al + ga1 + kb, &sAl[lb1]);                                              \
        gload16(Al + ga2 + kb, &sAl[lb2]);                                              \
        gload16(Bh + gb1 + kb, &sBh[lb1]);                                              \
        gload16(Bh + gb2 + kb, &sBh[lb2]);                                              \
        gload16(Bl + gb1 + kb, &sBl[lb1]);                                              \
        gload16(Bl + gb2 + kb, &sBl[lb2]);                                              \
        __syncthreads();                                                                \
        short8 ah[4], al[4], bh[4], bl[4];                                              \
        _Pragma("unroll")                                                               \
        for (int i = 0; i < 4; ++i) {                                                   \
            ah[i] = *(const short8*)&sAh[(wm + i * 16 + lm) * 32 + pq];                 \
            al[i] = *(const short8*)&sAl[(wm + i * 16 + lm) * 32 + pq];                 \
            bh[i] = *(const short8*)&sBh[(wn + i * 16 + lm) * 32 + pq];                 \
            bl[i] = *(const short8*)&sBl[(wn + i * 16 + lm) * 32 + pq];                 \
        }                                                                               \
        _Pragma("unroll")                                                               \
        for (int i = 0; i < 4; ++i)                                                     \
            _Pragma("unroll")                                                           \
            for (int j = 0; j < 4; ++j)                                                 \
                acc[i][j] = __builtin_amdgcn_mfma_f32_16x16x32_bf16(ah[i], bh[j], acc[i][j], 0, 0, 0); \
        _Pragma("unroll")                                                               \
        for (int i = 0; i < 4; ++i)                                                     \
            _Pragma("unroll")                                                           \
            for (int j = 0; j < 4; ++j)                                                 \
                acc[i][j] = __builtin_amdgcn_mfma_f32_16x16x32_bf16(ah[i], bl[j], acc[i][j], 0, 0, 0); \
        _Pragma("unroll")                                                               \
        for (int i = 0; i < 4; ++i)                                                     \
            _Pragma("unroll")                                                           \
            for (int j = 0; j < 4; ++j)                                                 \
                acc[i][j] = __builtin_amdgcn_mfma_f32_16x16x32_bf16(al[i], bh[j], acc[i][j], 0, 0, 0); \
    }

// in_proj: M=8192 (b,l), N=1024 (e), K=512. Epilogue scatter folds direction
// split + reverse:  e<256 -> x_t ; <512 -> z_t ; <768 -> x_t rev ; else z_t rev
// x_t/z_t: [4][4096][256] fp32
__global__ __launch_bounds__(256)
void k_in_proj_mfma(const unsigned short* __restrict__ Ah, const unsigned short* __restrict__ Al,
                    const unsigned short* __restrict__ Bh, const unsigned short* __restrict__ Bl,
                    float* __restrict__ x_t, float* __restrict__ z_t)
{
    __shared__ unsigned short sAh[128 * 32], sAl[128 * 32], sBh[128 * 32], sBl[128 * 32];
    GEMM_CORE(512)
    const int region = N0 >> 8;               // 0..3 uniform per block
    const int eobase = (N0 & 255) + wn;
    float* base = ((region & 1) == 0) ? x_t : z_t;
#pragma unroll
    for (int i = 0; i < 4; ++i) {
#pragma unroll
        for (int r = 0; r < 4; ++r) {
            int m = M0 + wm + i * 16 + q * 4 + r;
            int b = m >> 12, l = m & 4095;
            size_t rowoff = (region < 2)
                ? ((size_t)b * 4096 + l) * 256
                : ((size_t)(b + 2) * 4096 + (4095 - l)) * 256;
#pragma unroll
            for (int j = 0; j < 4; ++j)
                base[rowoff + eobase + j * 16 + lm] = acc[i][j][r];
        }
    }
}

// out_proj: M=8192 (b,l), N=512 (o), K=1024.  out row-major [8192][512] fp32
__global__ __launch_bounds__(256)
void k_out_proj_mfma(const unsigned short* __restrict__ Ah, const unsigned short* __restrict__ Al,
                     const unsigned short* __restrict__ Bh, const unsigned short* __restrict__ Bl,
                     float* __restrict__ out)
{
    __shared__ unsigned short sAh[128 * 32], sAl[128 * 32], sBh[128 * 32], sBl[128 * 32];
    GEMM_CORE(1024)
#pragma unroll
    for (int i = 0; i < 4; ++i) {
#pragma unroll
        for (int r = 0; r < 4; ++r) {
            size_t m = (size_t)(M0 + wm + i * 16 + q * 4 + r);
#pragma unroll
            for (int j = 0; j < 4; ++j)
                out[m * 512 + N0 + wn + j * 16 + lm] = acc[i][j][r];
        }
    }
}

// ============================================================================
// conv_x: dilated (8) causal depthwise conv + SiLU.  x_t -> u_t  [4][4096][256]
// ============================================================================
__global__ __launch_bounds__(256)
void k_conv_x(const float* __restrict__ x_t, const float* __restrict__ w,
              float* __restrict__ u_t)
{
    const int bid = blockIdx.x;
    const int b = bid >> 12, l = bid & 4095;
    const int d = threadIdx.x;
    const float* base = x_t + (size_t)b * 4096 * 256 + d;
    const float w0 = w[d*4+0], w1 = w[d*4+1], w2 = w[d*4+2], w3 = w[d*4+3];
    float acc = w3 * base[(size_t)l * 256];
    if (l >= 8)  acc += w2 * base[(size_t)(l - 8)  * 256];
    if (l >= 16) acc += w1 * base[(size_t)(l - 16) * 256];
    if (l >= 24) acc += w0 * base[(size_t)(l - 24) * 256];
    u_t[((size_t)b * 4096 + l) * 256 + d] = silu_f(acc);
}

// ============================================================================
// conv_z: dilation-1 causal conv + SiLU -> ybuf z-channels as bf16 hi/lo,
// direction un-reversal folded in. ybuf: [2][4096][1024]
// ============================================================================
__global__ __launch_bounds__(256)
void k_conv_z(const float* __restrict__ z_t, const float* __restrict__ w,
              unsigned short* __restrict__ ybh, unsigned short* __restrict__ ybl)
{
    const int bid = blockIdx.x;
    const int b = bid >> 12, l = bid & 4095;
    const int d = threadIdx.x;
    const float* base = z_t + (size_t)b * 4096 * 256 + d;
    const float w0 = w[d*4+0], w1 = w[d*4+1], w2 = w[d*4+2], w3 = w[d*4+3];
    float acc = w3 * base[(size_t)l * 256];
    if (l >= 1) acc += w2 * base[(size_t)(l - 1) * 256];
    if (l >= 2) acc += w1 * base[(size_t)(l - 2) * 256];
    if (l >= 3) acc += w0 * base[(size_t)(l - 3) * 256];
    float v = silu_f(acc);
    size_t oidx = (b < 2) ? ((size_t)b * 4096 + l) * 1024 + 256 + d
                          : ((size_t)(b - 2) * 4096 + (4095 - l)) * 1024 + 768 + d;
    unsigned short h = f2bf(v);
    ybh[oidx] = h;
    ybl[oidx] = f2bf(v - bf2f(h));
}

// ============================================================================
// x_proj: xdbl[m][e] = sum_d u_t[m][d] * Wx[e][d];  M=16384, N=48, K=256
// ============================================================================
__global__ __launch_bounds__(256)
void k_xproj(const float* __restrict__ U, const float* __restrict__ W,
             float* __restrict__ xdbl)
{
    __shared__ float As[32][132];
    __shared__ float Bs[32][52];
    const int t = threadIdx.x;
    const int m0 = blockIdx.x * 128;
    const int lrow = t >> 1;
    const int lk0  = (t & 1) * 16;
    const int tx = t & 15, ty = t >> 4;
    const int be = t >> 2;
    const int bk = (t & 3) * 8;
    float acc[8][3];
#pragma unroll
    for (int i = 0; i < 8; ++i) { acc[i][0] = 0.f; acc[i][1] = 0.f; acc[i][2] = 0.f; }

    for (int kb = 0; kb < 256; kb += 32) {
        const float* ap = U + ((size_t)(m0 + lrow)) * 256 + kb + lk0;
        float4 a0 = *(const float4*)(ap);
        float4 a1 = *(const float4*)(ap + 4);
        float4 a2 = *(const float4*)(ap + 8);
        float4 a3 = *(const float4*)(ap + 12);
        float4 b0, b1;
        if (be < 48) {
            const float* bp = W + (size_t)be * 256 + kb + bk;
            b0 = *(const float4*)(bp);
            b1 = *(const float4*)(bp + 4);
        }
        __syncthreads();
        As[lk0+ 0][lrow] = a0.x; As[lk0+ 1][lrow] = a0.y; As[lk0+ 2][lrow] = a0.z; As[lk0+ 3][lrow] = a0.w;
        As[lk0+ 4][lrow] = a1.x; As[lk0+ 5][lrow] = a1.y; As[lk0+ 6][lrow] = a1.z; As[lk0+ 7][lrow] = a1.w;
        As[lk0+ 8][lrow] = a2.x; As[lk0+ 9][lrow] = a2.y; As[lk0+10][lrow] = a2.z; As[lk0+11][lrow] = a2.w;
        As[lk0+12][lrow] = a3.x; As[lk0+13][lrow] = a3.y; As[lk0+14][lrow] = a3.z; As[lk0+15][lrow] = a3.w;
        if (be < 48) {
            Bs[bk+0][be] = b0.x; Bs[bk+1][be] = b0.y; Bs[bk+2][be] = b0.z; Bs[bk+3][be] = b0.w;
            Bs[bk+4][be] = b1.x; Bs[bk+5][be] = b1.y; Bs[bk+6][be] = b1.z; Bs[bk+7][be] = b1.w;
        }
        __syncthreads();
#pragma unroll
        for (int k = 0; k < 32; ++k) {
            float4 av0 = *(const float4*)&As[k][ty*8];
            float4 av1 = *(const float4*)&As[k][ty*8+4];
            float av[8] = {av0.x,av0.y,av0.z,av0.w,av1.x,av1.y,av1.z,av1.w};
            float bva = Bs[k][tx*3+0];
            float bvb = Bs[k][tx*3+1];
            float bvc = Bs[k][tx*3+2];
#pragma unroll
            for (int i = 0; i < 8; ++i) {
                acc[i][0] = fmaf(av[i], bva, acc[i][0]);
                acc[i][1] = fmaf(av[i], bvb, acc[i][1]);
                acc[i][2] = fmaf(av[i], bvc, acc[i][2]);
            }
        }
    }
#pragma unroll
    for (int i = 0; i < 8; ++i) {
        size_t row = (size_t)(m0 + ty * 8 + i) * 48 + tx * 3;
        xdbl[row + 0] = acc[i][0];
        xdbl[row + 1] = acc[i][1];
        xdbl[row + 2] = acc[i][2];
    }
}

// ============================================================================
// dt_proj + softplus
// ============================================================================
__global__ __launch_bounds__(256)
void k_dtproj(const float* __restrict__ xdbl, const float* __restrict__ Wdt,
              const float* __restrict__ bdt, float* __restrict__ delta_t)
{
    __shared__ float As[32][68];
    __shared__ float Bs[32][132];
    const int t  = threadIdx.x;
    const int m0 = blockIdx.x * 64;
    const int n0 = blockIdx.y * 128;
    const int ai = t >> 2, ak = (t & 3) * 8;
    const int be = t >> 1, bk = (t & 1) * 16;
    {
        const float* ap = xdbl + (size_t)(m0 + ai) * 48 + ak;
        float4 a0 = *(const float4*)(ap);
        float4 a1 = *(const float4*)(ap + 4);
        const float* bp = Wdt + (size_t)(n0 + be) * 32 + bk;
        float4 b0 = *(const float4*)(bp);
        float4 b1 = *(const float4*)(bp + 4);
        float4 b2 = *(const float4*)(bp + 8);
        float4 b3 = *(const float4*)(bp + 12);
        As[ak+0][ai] = a0.x; As[ak+1][ai] = a0.y; As[ak+2][ai] = a0.z; As[ak+3][ai] = a0.w;
        As[ak+4][ai] = a1.x; As[ak+5][ai] = a1.y; As[ak+6][ai] = a1.z; As[ak+7][ai] = a1.w;
        Bs[bk+ 0][be] = b0.x; Bs[bk+ 1][be] = b0.y; Bs[bk+ 2][be] = b0.z; Bs[bk+ 3][be] = b0.w;
        Bs[bk+ 4][be] = b1.x; Bs[bk+ 5][be] = b1.y; Bs[bk+ 6][be] = b1.z; Bs[bk+ 7][be] = b1.w;
        Bs[bk+ 8][be] = b2.x; Bs[bk+ 9][be] = b2.y; Bs[bk+10][be] = b2.z; Bs[bk+11][be] = b2.w;
        Bs[bk+12][be] = b3.x; Bs[bk+13][be] = b3.y; Bs[bk+14][be] = b3.z; Bs[bk+15][be] = b3.w;
    }
    __syncthreads();
    const int tx = t & 15, ty = t >> 4;
    float acc[4][8];
#pragma unroll
    for (int i = 0; i < 4; ++i)
#pragma unroll
        for (int j = 0; j < 8; ++j) acc[i][j] = 0.0f;
#pragma unroll
    for (int k = 0; k < 32; ++k) {
        float4 a4  = *(const float4*)&As[k][ty*4];
        float4 bv0 = *(const float4*)&Bs[k][tx*8];
        float4 bv1 = *(const float4*)&Bs[k][tx*8+4];
        float av[4] = {a4.x, a4.y, a4.z, a4.w};
        float bv[8] = {bv0.x,bv0.y,bv0.z,bv0.w,bv1.x,bv1.y,bv1.z,bv1.w};
#pragma unroll
        for (int i = 0; i < 4; ++i)
#pragma unroll
            for (int j = 0; j < 8; ++j)
                acc[i][j] = fmaf(av[i], bv[j], acc[i][j]);
    }
    float bias[8];
#pragma unroll
    for (int j = 0; j < 8; ++j) bias[j] = bdt[n0 + tx*8 + j];
#pragma unroll
    for (int i = 0; i < 4; ++i) {
        size_t m = (size_t)(m0 + ty * 4 + i);
        float4 o0, o1;
        o0.x = softplus_f(acc[i][0] + bias[0]);
        o0.y = softplus_f(acc[i][1] + bias[1]);
        o0.z = softplus_f(acc[i][2] + bias[2]);
        o0.w = softplus_f(acc[i][3] + bias[3]);
        o1.x = softplus_f(acc[i][4] + bias[4]);
        o1.y = softplus_f(acc[i][5] + bias[5]);
        o1.z = softplus_f(acc[i][6] + bias[6]);
        o1.w = softplus_f(acc[i][7] + bias[7]);
        float* dst = delta_t + m * 256 + n0 + tx * 8;
        *(float4*)(dst)     = o0;
        *(float4*)(dst + 4) = o1;
    }
}

// ============================================================================
// Selective scan, chunked (NCHUNK=128 chunks x CLEN=32 steps).
// ============================================================================
__global__ __launch_bounds__(256)
void k_scan1(const float* __restrict__ delta_t, const float* __restrict__ u_t,
             const float* __restrict__ xdbl, const float* __restrict__ A_log,
             float* __restrict__ chS, float* __restrict__ chB)
{
    __shared__ float Bsh[8][CLEN];
    const int b = blockIdx.x >> 7;
    const int c = blockIdx.x & 127;
    const int d = threadIdx.x;
    const int l0 = c * CLEN;
    {
        int s = threadIdx.x;   // 256 = 8*32 exactly
        int i = s >> 3, n = s & 7;
        Bsh[n][i] = xdbl[((size_t)b * 4096 + l0 + i) * 48 + 32 + n];
    }
    float a[8];
#pragma unroll
    for (int n = 0; n < 8; ++n) a[n] = -__expf(A_log[d * 8 + n]);
    float h[8];
#pragma unroll
    for (int n = 0; n < 8; ++n) h[n] = 0.0f;
    float S = 0.0f;
    __syncthreads();
    const float* dp = delta_t + ((size_t)b * 4096 + l0) * 256 + d;
    const float* up = u_t     + ((size_t)b * 4096 + l0) * 256 + d;
    for (int i = 0; i < CLEN; ++i) {
        float dlt = dp[(size_t)i * 256];
        float u   = up[(size_t)i * 256];
        float du  = dlt * u;
        S += dlt;
#pragma unroll
        for (int n = 0; n < 8; ++n) {
            float dA = __expf(dlt * a[n]);
            h[n] = dA * h[n] + du * Bsh[n][i];
        }
    }
    chS[((size_t)b * NCHUNK + c) * 256 + d] = S;
#pragma unroll
    for (int n = 0; n < 8; ++n)
        chB[(((size_t)b * NCHUNK + c) * 8 + n) * 256 + d] = h[n];
}

__global__ __launch_bounds__(256)
void k_scan2(const float* __restrict__ chS, const float* __restrict__ chB,
             const float* __restrict__ A_log, float* __restrict__ hinit)
{
    const int b = blockIdx.x >> 3;
    const int n = blockIdx.x & 7;
    const int d = threadIdx.x;
    const float a = -__expf(A_log[d * 8 + n]);
    float h = 0.0f;
    for (int c = 0; c < NCHUNK; ++c) {
        size_t idx = (((size_t)b * NCHUNK + c) * 8 + n) * 256 + d;
        hinit[idx] = h;
        float S = chS[((size_t)b * NCHUNK + c) * 256 + d];
        h = __expf(a * S) * h + chB[idx];
    }
}

__global__ __launch_bounds__(256)
void k_scan3(const float* __restrict__ delta_t, const float* __restrict__ u_t,
             const float* __restrict__ xdbl, const float* __restrict__ A_log,
             const float* __restrict__ Dp, const float* __restrict__ hinit,
             unsigned short* __restrict__ ybh, unsigned short* __restrict__ ybl)
{
    __shared__ float Bsh[8][CLEN];
    __shared__ float Csh[8][CLEN];
    const int b = blockIdx.x >> 7;
    const int c = blockIdx.x & 127;
    const int d = threadIdx.x;
    const int l0 = c * CLEN;
    {
        int s = threadIdx.x;
        int i = s >> 3, n = s & 7;
        size_t row = ((size_t)b * 4096 + l0 + i) * 48;
        Bsh[n][i] = xdbl[row + 32 + n];
        Csh[n][i] = xdbl[row + 40 + n];
    }
    float a[8], h[8];
#pragma unroll
    for (int n = 0; n < 8; ++n) {
        a[n] = -__expf(A_log[d * 8 + n]);
        h[n] = hinit[(((size_t)b * NCHUNK + c) * 8 + n) * 256 + d];
    }
    const float Dd = Dp[d];
    __syncthreads();
    const float* dp = delta_t + ((size_t)b * 4096 + l0) * 256 + d;
    const float* up = u_t     + ((size_t)b * 4096 + l0) * 256 + d;
    for (int i = 0; i < CLEN; ++i) {
        float dlt = dp[(size_t)i * 256];
        float u   = up[(size_t)i * 256];
        float du  = dlt * u;
        float y   = u * Dd;
#pragma unroll
        for (int n = 0; n < 8; ++n) {
            float dA = __expf(dlt * a[n]);
            h[n] = dA * h[n] + du * Bsh[n][i];
            y += h[n] * Csh[n][i];
        }
        int l = l0 + i;
        size_t oidx = (b < 2) ? ((size_t)b * 4096 + l) * 1024 + d
                              : ((size_t)(b - 2) * 4096 + (4095 - l)) * 1024 + 512 + d;
        unsigned short hh = f2bf(y);
        ybh[oidx] = hh;
        ybl[oidx] = f2bf(y - bf2f(hh));
    }
}

// ============================================================================
extern "C" void kernel_launch(void* const* d_in, const int* in_sizes, int n_in,
                              void* d_out, int out_size, void* d_ws, size_t ws_size,
                              hipStream_t stream)
{
    const float* hs    = (const float*)d_in[0];   // (2,4096,512)
    const float* w_in  = (const float*)d_in[1];   // (1024,512)
    const float* w_xp  = (const float*)d_in[2];   // (48,256)
    const float* w_dt  = (const float*)d_in[3];   // (256,32)
    const float* b_dt  = (const float*)d_in[4];   // (256,)
    const float* A_log = (const float*)d_in[5];   // (256,8)
    const float* Dpar  = (const float*)d_in[6];   // (256,)
    const float* w_cx  = (const float*)d_in[7];   // (256,1,4)
    const float* w_cz  = (const float*)d_in[8];   // (256,1,4)
    const float* w_out = (const float*)d_in[9];   // (512,1024)
    float* out = (float*)d_out;                   // (2,4096,512)

    float* ws = (float*)d_ws;
    const size_t NX = (size_t)4 * 4096 * 256;       // 4,194,304 floats
    float* x_t  = ws;                               // [4][4096][256] fp32 (dead after conv_x)
    float* z_t  = ws + NX;                          // [4][4096][256] fp32
    float* u_t  = ws + 2 * NX;                      // [4][4096][256] fp32
    float* dlt  = ws + 3 * NX;                      // [4][4096][256] fp32
    float* xdbl = ws + 4 * NX;                      // [4][4096][48]
    float* chS  = xdbl + 786432;                    // [4][128][256]
    float* chB  = chS + 131072;                     // [4][128][8][256]
    float* hin  = chB + 1048576;                    // [4][128][8][256]
    unsigned short* hsh = (unsigned short*)(hin + 1048576);  // [8192][512] bf16 (dead after in_proj)
    unsigned short* hsl = hsh + 4194304;                     // [8192][512] bf16 (dead after in_proj)
    unsigned short* wih = hsl + 4194304;            // [1024][512] bf16
    unsigned short* wil = wih + 524288;
    unsigned short* woh = wil + 524288;             // [512][1024] bf16
    unsigned short* wol = woh + 524288;
    // aliases (stream order makes these safe):
    unsigned short* ybh = (unsigned short*)x_t;     // [2][4096][1024] bf16  (over dead x_t)
    unsigned short* ybl = hsh;                      // [2][4096][1024] bf16  (over dead hs hi/lo)

    k_cast_hilo    <<<4096,         256, 0, stream>>>(hs,    hsh, hsl, 1048576);
    k_cast_hilo    <<<512,          256, 0, stream>>>(w_in,  wih, wil, 131072);
    k_cast_hilo    <<<512,          256, 0, stream>>>(w_out, woh, wol, 131072);
    k_in_proj_mfma <<<dim3(8, 64),  256, 0, stream>>>(hsh, hsl, wih, wil, x_t, z_t);
    k_conv_x       <<<16384,        256, 0, stream>>>(x_t, w_cx, u_t);
    k_conv_z       <<<16384,        256, 0, stream>>>(z_t, w_cz, ybh, ybl);
    k_xproj        <<<128,          256, 0, stream>>>(u_t, w_xp, xdbl);
    k_dtproj       <<<dim3(256, 2), 256, 0, stream>>>(xdbl, w_dt, b_dt, dlt);
    k_scan1        <<<512,          256, 0, stream>>>(dlt, u_t, xdbl, A_log, chS, chB);
    k_scan2        <<<32,           256, 0, stream>>>(chS, chB, A_log, hin);
    k_scan3        <<<512,          256, 0, stream>>>(dlt, u_t, xdbl, A_log, Dpar, hin, ybh, ybl);
    k_out_proj_mfma<<<dim3(4, 64),  256, 0, stream>>>(ybh, ybl, woh, wol, out);
}

// Round 3
// 295.390 us; speedup vs baseline: 1.5984x; 1.0508x over previous
//
#include <hip/hip_runtime.h>
#include <math.h>

// Problem constants
#define LSEQ   4096
#define DHALF  256
#define NSTATE 8
#define NCHUNK 128           // scan chunks
#define CLEN   32            // chunk length (NCHUNK*CLEN = 4096)

typedef __attribute__((ext_vector_type(8))) short short8;   // 8 x bf16 fragment
typedef __attribute__((ext_vector_type(4))) float f32x4;
typedef __attribute__((ext_vector_type(4))) unsigned short us4;

__device__ __forceinline__ float silu_f(float v)     { return v / (1.0f + __expf(-v)); }
__device__ __forceinline__ float softplus_f(float v) { return v > 20.0f ? v : log1pf(__expf(v)); }

__device__ __forceinline__ unsigned short f2bf(float f) {
    unsigned int u = __float_as_uint(f);
    return (unsigned short)((u + 0x7fffu + ((u >> 16) & 1u)) >> 16);
}
__device__ __forceinline__ float bf2f(unsigned short h) {
    return __uint_as_float(((unsigned int)h) << 16);
}

// async global->LDS, 16B per lane; LDS dest = wave-uniform base + lane*16
__device__ __forceinline__ void gload16(const void* g, void* l) {
    __builtin_amdgcn_global_load_lds((const __attribute__((address_space(1))) void*)g,
                                     (__attribute__((address_space(3))) void*)l, 16, 0, 0);
}

// ============================================================================
// fp32 -> bf16 hi/lo split cast, all 3 tensors in one launch.
// seg0: hs (n4=1048576), seg1: w_in (131072), seg2: w_out (131072)
// ============================================================================
__global__ __launch_bounds__(256)
void k_cast_all(const float* __restrict__ s0, unsigned short* __restrict__ h0, unsigned short* __restrict__ l0,
                const float* __restrict__ s1, unsigned short* __restrict__ h1, unsigned short* __restrict__ l1,
                const float* __restrict__ s2, unsigned short* __restrict__ h2, unsigned short* __restrict__ l2)
{
    int i = blockIdx.x * 256 + threadIdx.x;
    const float* src; unsigned short* hi; unsigned short* lo; int off;
    if (i < 1048576)      { src = s0; hi = h0; lo = l0; off = i; }
    else if (i < 1179648) { src = s1; hi = h1; lo = l1; off = i - 1048576; }
    else                  { src = s2; hi = h2; lo = l2; off = i - 1179648; }
    float4 v = ((const float4*)src)[off];
    us4 h, l;
    h.x = f2bf(v.x); l.x = f2bf(v.x - bf2f(h.x));
    h.y = f2bf(v.y); l.y = f2bf(v.y - bf2f(h.y));
    h.z = f2bf(v.z); l.z = f2bf(v.z - bf2f(h.z));
    h.w = f2bf(v.w); l.w = f2bf(v.w - bf2f(h.w));
    ((us4*)hi)[off] = h;
    ((us4*)lo)[off] = l;
}

// ============================================================================
// MFMA bt-GEMM core (C = A * B^T), bf16 hi/lo split (3 products).
// 128(M) x 64(N) tile / block, 4 waves each 64x32 via 4x2 16x16x32 MFMAs.
// LDS 16B chunks XOR-swizzled by ((row>>1)&3): 2-way bank alias = free.
// Swizzle applied on the per-lane GLOBAL address (LDS dst stays
// wave-uniform base + lane*16 per the global_load_lds constraint).
// ============================================================================
#define GEMM_CORE64(K_)                                                                 \
    const int t = threadIdx.x;                                                          \
    const int wv = t >> 6, lane = t & 63;                                               \
    const int wm = (wv & 1) * 64, wn = (wv >> 1) * 32;                                  \
    const int lm = lane & 15, q = lane >> 4;                                            \
    const int M0 = blockIdx.y * 128, N0 = blockIdx.x * 64;                              \
    const int slot = lane & 3;                                                          \
    const int rA1 = wv * 32 + (lane >> 2);                                              \
    const int rA2 = rA1 + 16;                                                           \
    const int rB  = wv * 16 + (lane >> 2);                                              \
    const int cA1 = slot ^ ((rA1 >> 1) & 3);                                            \
    const int cA2 = slot ^ ((rA2 >> 1) & 3);                                            \
    const int cB  = slot ^ ((rB  >> 1) & 3);                                            \
    const int lbA1 = wv * 1024, lbA2 = lbA1 + 512;   /* ushort idx, wave-uniform */     \
    const int lbB  = wv * 512;                                                          \
    const int pq = (q ^ ((lm >> 1) & 3)) * 8;                                           \
    const size_t gA1 = (size_t)(M0 + rA1) * K_ + cA1 * 8;                               \
    const size_t gA2 = (size_t)(M0 + rA2) * K_ + cA2 * 8;                               \
    const size_t gB1 = (size_t)(N0 + rB ) * K_ + cB  * 8;                               \
    f32x4 acc[4][2] = {};                                                               \
    for (int kb = 0; kb < K_; kb += 32) {                                               \
        __syncthreads();                                                                \
        gload16(Ah + gA1 + kb, &sAh[lbA1]);                                             \
        gload16(Ah + gA2 + kb, &sAh[lbA2]);                                             \
        gload16(Al + gA1 + kb, &sAl[lbA1]);                                             \
        gload16(Al + gA2 + kb, &sAl[lbA2]);                                             \
        gload16(Bh + gB1 + kb, &sBh[lbB]);                                              \
        gload16(Bl + gB1 + kb, &sBl[lbB]);                                              \
        __syncthreads();                                                                \
        short8 ah[4], al[4], bh[2], bl[2];                                              \
        _Pragma("unroll")                                                               \
        for (int i = 0; i < 4; ++i) {                                                   \
            ah[i] = *(const short8*)&sAh[(wm + i * 16 + lm) * 32 + pq];                 \
            al[i] = *(const short8*)&sAl[(wm + i * 16 + lm) * 32 + pq];                 \
        }                                                                               \
        _Pragma("unroll")                                                               \
        for (int j = 0; j < 2; ++j) {                                                   \
            bh[j] = *(const short8*)&sBh[(wn + j * 16 + lm) * 32 + pq];                 \
            bl[j] = *(const short8*)&sBl[(wn + j * 16 + lm) * 32 + pq];                 \
        }                                                                               \
        _Pragma("unroll")                                                               \
        for (int i = 0; i < 4; ++i)                                                     \
            _Pragma("unroll")                                                           \
            for (int j = 0; j < 2; ++j)                                                 \
                acc[i][j] = __builtin_amdgcn_mfma_f32_16x16x32_bf16(ah[i], bh[j], acc[i][j], 0, 0, 0); \
        _Pragma("unroll")                                                               \
        for (int i = 0; i < 4; ++i)                                                     \
            _Pragma("unroll")                                                           \
            for (int j = 0; j < 2; ++j)                                                 \
                acc[i][j] = __builtin_amdgcn_mfma_f32_16x16x32_bf16(ah[i], bl[j], acc[i][j], 0, 0, 0); \
        _Pragma("unroll")                                                               \
        for (int i = 0; i < 4; ++i)                                                     \
            _Pragma("unroll")                                                           \
            for (int j = 0; j < 2; ++j)                                                 \
                acc[i][j] = __builtin_amdgcn_mfma_f32_16x16x32_bf16(al[i], bh[j], acc[i][j], 0, 0, 0); \
    }

// in_proj: M=8192 (b,l), N=1024 (e), K=512. Epilogue scatter folds direction
// split + reverse. grid (16,64) = 1024 blocks = 4/CU.
__global__ __launch_bounds__(256)
void k_in_proj_mfma(const unsigned short* __restrict__ Ah, const unsigned short* __restrict__ Al,
                    const unsigned short* __restrict__ Bh, const unsigned short* __restrict__ Bl,
                    float* __restrict__ x_t, float* __restrict__ z_t)
{
    __shared__ unsigned short sAh[128 * 32], sAl[128 * 32], sBh[64 * 32], sBl[64 * 32];
    GEMM_CORE64(512)
    const int region = N0 >> 8;               // 0..3 uniform per block (64 | 256)
    const int eobase = (N0 & 255) + wn;
    float* base = ((region & 1) == 0) ? x_t : z_t;
#pragma unroll
    for (int i = 0; i < 4; ++i) {
#pragma unroll
        for (int r = 0; r < 4; ++r) {
            int m = M0 + wm + i * 16 + q * 4 + r;
            int b = m >> 12, l = m & 4095;
            size_t rowoff = (region < 2)
                ? ((size_t)b * 4096 + l) * 256
                : ((size_t)(b + 2) * 4096 + (4095 - l)) * 256;
#pragma unroll
            for (int j = 0; j < 2; ++j)
                base[rowoff + eobase + j * 16 + lm] = acc[i][j][r];
        }
    }
}

// out_proj: M=8192 (b,l), N=512 (o), K=1024. grid (8,64) = 512 blocks = 2/CU.
__global__ __launch_bounds__(256)
void k_out_proj_mfma(const unsigned short* __restrict__ Ah, const unsigned short* __restrict__ Al,
                     const unsigned short* __restrict__ Bh, const unsigned short* __restrict__ Bl,
                     float* __restrict__ out)
{
    __shared__ unsigned short sAh[128 * 32], sAl[128 * 32], sBh[64 * 32], sBl[64 * 32];
    GEMM_CORE64(1024)
#pragma unroll
    for (int i = 0; i < 4; ++i) {
#pragma unroll
        for (int r = 0; r < 4; ++r) {
            size_t m = (size_t)(M0 + wm + i * 16 + q * 4 + r);
#pragma unroll
            for (int j = 0; j < 2; ++j)
                out[m * 512 + N0 + wn + j * 16 + lm] = acc[i][j][r];
        }
    }
}

// ============================================================================
// conv_x: dilated (8) causal depthwise conv + SiLU, float4 over channels.
// 1,048,576 threads; thread -> (b, l, d0=4*g). x_t -> u_t [4][4096][256]
// ============================================================================
__global__ __launch_bounds__(256)
void k_conv_x4(const float* __restrict__ x_t, const float* __restrict__ w,
               float* __restrict__ u_t)
{
    int idx = blockIdx.x * 256 + threadIdx.x;
    int b = idx >> 18, rem = idx & 262143;
    int l = rem >> 6, d0 = (rem & 63) * 4;
    const float* base = x_t + (size_t)b * 4096 * 256 + d0;
    float4 wv0 = *(const float4*)(w + (d0 + 0) * 4);
    float4 wv1 = *(const float4*)(w + (d0 + 1) * 4);
    float4 wv2 = *(const float4*)(w + (d0 + 2) * 4);
    float4 wv3 = *(const float4*)(w + (d0 + 3) * 4);
    float4 tp = *(const float4*)(base + (size_t)l * 256);
    float4 a = make_float4(wv0.w * tp.x, wv1.w * tp.y, wv2.w * tp.z, wv3.w * tp.w);
    if (l >= 8) {
        tp = *(const float4*)(base + (size_t)(l - 8) * 256);
        a.x += wv0.z * tp.x; a.y += wv1.z * tp.y; a.z += wv2.z * tp.z; a.w += wv3.z * tp.w;
    }
    if (l >= 16) {
        tp = *(const float4*)(base + (size_t)(l - 16) * 256);
        a.x += wv0.y * tp.x; a.y += wv1.y * tp.y; a.z += wv2.y * tp.z; a.w += wv3.y * tp.w;
    }
    if (l >= 24) {
        tp = *(const float4*)(base + (size_t)(l - 24) * 256);
        a.x += wv0.x * tp.x; a.y += wv1.x * tp.y; a.z += wv2.x * tp.z; a.w += wv3.x * tp.w;
    }
    float4 o = make_float4(silu_f(a.x), silu_f(a.y), silu_f(a.z), silu_f(a.w));
    *(float4*)(u_t + ((size_t)b * 4096 + l) * 256 + d0) = o;
}

// ============================================================================
// conv_z: dilation-1 causal conv + SiLU -> ybuf z-channels as bf16 hi/lo,
// direction un-reversal folded in. ybuf: [2][4096][1024]
// ============================================================================
__global__ __launch_bounds__(256)
void k_conv_z4(const float* __restrict__ z_t, const float* __restrict__ w,
               unsigned short* __restrict__ ybh, unsigned short* __restrict__ ybl)
{
    int idx = blockIdx.x * 256 + threadIdx.x;
    int b = idx >> 18, rem = idx & 262143;
    int l = rem >> 6, d0 = (rem & 63) * 4;
    const float* base = z_t + (size_t)b * 4096 * 256 + d0;
    float4 wv0 = *(const float4*)(w + (d0 + 0) * 4);
    float4 wv1 = *(const float4*)(w + (d0 + 1) * 4);
    float4 wv2 = *(const float4*)(w + (d0 + 2) * 4);
    float4 wv3 = *(const float4*)(w + (d0 + 3) * 4);
    float4 tp = *(const float4*)(base + (size_t)l * 256);
    float4 a = make_float4(wv0.w * tp.x, wv1.w * tp.y, wv2.w * tp.z, wv3.w * tp.w);
    if (l >= 1) {
        tp = *(const float4*)(base + (size_t)(l - 1) * 256);
        a.x += wv0.z * tp.x; a.y += wv1.z * tp.y; a.z += wv2.z * tp.z; a.w += wv3.z * tp.w;
    }
    if (l >= 2) {
        tp = *(const float4*)(base + (size_t)(l - 2) * 256);
        a.x += wv0.y * tp.x; a.y += wv1.y * tp.y; a.z += wv2.y * tp.z; a.w += wv3.y * tp.w;
    }
    if (l >= 3) {
        tp = *(const float4*)(base + (size_t)(l - 3) * 256);
        a.x += wv0.x * tp.x; a.y += wv1.x * tp.y; a.z += wv2.x * tp.z; a.w += wv3.x * tp.w;
    }
    float v0 = silu_f(a.x), v1 = silu_f(a.y), v2 = silu_f(a.z), v3 = silu_f(a.w);
    size_t oidx = (b < 2) ? ((size_t)b * 4096 + l) * 1024 + 256 + d0
                          : ((size_t)(b - 2) * 4096 + (4095 - l)) * 1024 + 768 + d0;
    us4 h, lo;
    h.x = f2bf(v0); lo.x = f2bf(v0 - bf2f(h.x));
    h.y = f2bf(v1); lo.y = f2bf(v1 - bf2f(h.y));
    h.z = f2bf(v2); lo.z = f2bf(v2 - bf2f(h.z));
    h.w = f2bf(v3); lo.w = f2bf(v3 - bf2f(h.w));
    *(us4*)(ybh + oidx) = h;
    *(us4*)(ybl + oidx) = lo;
}

// ============================================================================
// x_proj: xdbl[m][e] = sum_d u_t[m][d] * Wx[e][d];  M=16384, N=48, K=256
// ============================================================================
__global__ __launch_bounds__(256)
void k_xproj(const float* __restrict__ U, const float* __restrict__ W,
             float* __restrict__ xdbl)
{
    __shared__ float As[32][132];
    __shared__ float Bs[32][52];
    const int t = threadIdx.x;
    const int m0 = blockIdx.x * 128;
    const int lrow = t >> 1;
    const int lk0  = (t & 1) * 16;
    const int tx = t & 15, ty = t >> 4;
    const int be = t >> 2;
    const int bk = (t & 3) * 8;
    float acc[8][3];
#pragma unroll
    for (int i = 0; i < 8; ++i) { acc[i][0] = 0.f; acc[i][1] = 0.f; acc[i][2] = 0.f; }

    for (int kb = 0; kb < 256; kb += 32) {
        const float* ap = U + ((size_t)(m0 + lrow)) * 256 + kb + lk0;
        float4 a0 = *(const float4*)(ap);
        float4 a1 = *(const float4*)(ap + 4);
        float4 a2 = *(const float4*)(ap + 8);
        float4 a3 = *(const float4*)(ap + 12);
        float4 b0, b1;
        if (be < 48) {
            const float* bp = W + (size_t)be * 256 + kb + bk;
            b0 = *(const float4*)(bp);
            b1 = *(const float4*)(bp + 4);
        }
        __syncthreads();
        As[lk0+ 0][lrow] = a0.x; As[lk0+ 1][lrow] = a0.y; As[lk0+ 2][lrow] = a0.z; As[lk0+ 3][lrow] = a0.w;
        As[lk0+ 4][lrow] = a1.x; As[lk0+ 5][lrow] = a1.y; As[lk0+ 6][lrow] = a1.z; As[lk0+ 7][lrow] = a1.w;
        As[lk0+ 8][lrow] = a2.x; As[lk0+ 9][lrow] = a2.y; As[lk0+10][lrow] = a2.z; As[lk0+11][lrow] = a2.w;
        As[lk0+12][lrow] = a3.x; As[lk0+13][lrow] = a3.y; As[lk0+14][lrow] = a3.z; As[lk0+15][lrow] = a3.w;
        if (be < 48) {
            Bs[bk+0][be] = b0.x; Bs[bk+1][be] = b0.y; Bs[bk+2][be] = b0.z; Bs[bk+3][be] = b0.w;
            Bs[bk+4][be] = b1.x; Bs[bk+5][be] = b1.y; Bs[bk+6][be] = b1.z; Bs[bk+7][be] = b1.w;
        }
        __syncthreads();
#pragma unroll
        for (int k = 0; k < 32; ++k) {
            float4 av0 = *(const float4*)&As[k][ty*8];
            float4 av1 = *(const float4*)&As[k][ty*8+4];
            float av[8] = {av0.x,av0.y,av0.z,av0.w,av1.x,av1.y,av1.z,av1.w};
            float bva = Bs[k][tx*3+0];
            float bvb = Bs[k][tx*3+1];
            float bvc = Bs[k][tx*3+2];
#pragma unroll
            for (int i = 0; i < 8; ++i) {
                acc[i][0] = fmaf(av[i], bva, acc[i][0]);
                acc[i][1] = fmaf(av[i], bvb, acc[i][1]);
                acc[i][2] = fmaf(av[i], bvc, acc[i][2]);
            }
        }
    }
#pragma unroll
    for (int i = 0; i < 8; ++i) {
        size_t row = (size_t)(m0 + ty * 8 + i) * 48 + tx * 3;
        xdbl[row + 0] = acc[i][0];
        xdbl[row + 1] = acc[i][1];
        xdbl[row + 2] = acc[i][2];
    }
}

// ============================================================================
// dt_proj + softplus
// ============================================================================
__global__ __launch_bounds__(256)
void k_dtproj(const float* __restrict__ xdbl, const float* __restrict__ Wdt,
              const float* __restrict__ bdt, float* __restrict__ delta_t)
{
    __shared__ float As[32][68];
    __shared__ float Bs[32][132];
    const int t  = threadIdx.x;
    const int m0 = blockIdx.x * 64;
    const int n0 = blockIdx.y * 128;
    const int ai = t >> 2, ak = (t & 3) * 8;
    const int be = t >> 1, bk = (t & 1) * 16;
    {
        const float* ap = xdbl + (size_t)(m0 + ai) * 48 + ak;
        float4 a0 = *(const float4*)(ap);
        float4 a1 = *(const float4*)(ap + 4);
        const float* bp = Wdt + (size_t)(n0 + be) * 32 + bk;
        float4 b0 = *(const float4*)(bp);
        float4 b1 = *(const float4*)(bp + 4);
        float4 b2 = *(const float4*)(bp + 8);
        float4 b3 = *(const float4*)(bp + 12);
        As[ak+0][ai] = a0.x; As[ak+1][ai] = a0.y; As[ak+2][ai] = a0.z; As[ak+3][ai] = a0.w;
        As[ak+4][ai] = a1.x; As[ak+5][ai] = a1.y; As[ak+6][ai] = a1.z; As[ak+7][ai] = a1.w;
        Bs[bk+ 0][be] = b0.x; Bs[bk+ 1][be] = b0.y; Bs[bk+ 2][be] = b0.z; Bs[bk+ 3][be] = b0.w;
        Bs[bk+ 4][be] = b1.x; Bs[bk+ 5][be] = b1.y; Bs[bk+ 6][be] = b1.z; Bs[bk+ 7][be] = b1.w;
        Bs[bk+ 8][be] = b2.x; Bs[bk+ 9][be] = b2.y; Bs[bk+10][be] = b2.z; Bs[bk+11][be] = b2.w;
        Bs[bk+12][be] = b3.x; Bs[bk+13][be] = b3.y; Bs[bk+14][be] = b3.z; Bs[bk+15][be] = b3.w;
    }
    __syncthreads();
    const int tx = t & 15, ty = t >> 4;
    float acc[4][8];
#pragma unroll
    for (int i = 0; i < 4; ++i)
#pragma unroll
        for (int j = 0; j < 8; ++j) acc[i][j] = 0.0f;
#pragma unroll
    for (int k = 0; k < 32; ++k) {
        float4 a4  = *(const float4*)&As[k][ty*4];
        float4 bv0 = *(const float4*)&Bs[k][tx*8];
        float4 bv1 = *(const float4*)&Bs[k][tx*8+4];
        float av[4] = {a4.x, a4.y, a4.z, a4.w};
        float bv[8] = {bv0.x,bv0.y,bv0.z,bv0.w,bv1.x,bv1.y,bv1.z,bv1.w};
#pragma unroll
        for (int i = 0; i < 4; ++i)
#pragma unroll
            for (int j = 0; j < 8; ++j)
                acc[i][j] = fmaf(av[i], bv[j], acc[i][j]);
    }
    float bias[8];
#pragma unroll
    for (int j = 0; j < 8; ++j) bias[j] = bdt[n0 + tx*8 + j];
#pragma unroll
    for (int i = 0; i < 4; ++i) {
        size_t m = (size_t)(m0 + ty * 4 + i);
        float4 o0, o1;
        o0.x = softplus_f(acc[i][0] + bias[0]);
        o0.y = softplus_f(acc[i][1] + bias[1]);
        o0.z = softplus_f(acc[i][2] + bias[2]);
        o0.w = softplus_f(acc[i][3] + bias[3]);
        o1.x = softplus_f(acc[i][4] + bias[4]);
        o1.y = softplus_f(acc[i][5] + bias[5]);
        o1.z = softplus_f(acc[i][6] + bias[6]);
        o1.w = softplus_f(acc[i][7] + bias[7]);
        float* dst = delta_t + m * 256 + n0 + tx * 8;
        *(float4*)(dst)     = o0;
        *(float4*)(dst + 4) = o1;
    }
}

// ============================================================================
// Selective scan, chunked (NCHUNK=128 chunks x CLEN=32 steps).
// ============================================================================
__global__ __launch_bounds__(256)
void k_scan1(const float* __restrict__ delta_t, const float* __restrict__ u_t,
             const float* __restrict__ xdbl, const float* __restrict__ A_log,
             float* __restrict__ chS, float* __restrict__ chB)
{
    __shared__ float Bsh[8][CLEN];
    const int b = blockIdx.x >> 7;
    const int c = blockIdx.x & 127;
    const int d = threadIdx.x;
    const int l0 = c * CLEN;
    {
        int s = threadIdx.x;   // 256 = 8*32 exactly
        int i = s >> 3, n = s & 7;
        Bsh[n][i] = xdbl[((size_t)b * 4096 + l0 + i) * 48 + 32 + n];
    }
    float a[8];
#pragma unroll
    for (int n = 0; n < 8; ++n) a[n] = -__expf(A_log[d * 8 + n]);
    float h[8];
#pragma unroll
    for (int n = 0; n < 8; ++n) h[n] = 0.0f;
    float S = 0.0f;
    __syncthreads();
    const float* dp = delta_t + ((size_t)b * 4096 + l0) * 256 + d;
    const float* up = u_t     + ((size_t)b * 4096 + l0) * 256 + d;
    for (int i = 0; i < CLEN; ++i) {
        float dlt = dp[(size_t)i * 256];
        float u   = up[(size_t)i * 256];
        float du  = dlt * u;
        S += dlt;
#pragma unroll
        for (int n = 0; n < 8; ++n) {
            float dA = __expf(dlt * a[n]);
            h[n] = dA * h[n] + du * Bsh[n][i];
        }
    }
    chS[((size_t)b * NCHUNK + c) * 256 + d] = S;
#pragma unroll
    for (int n = 0; n < 8; ++n)
        chB[(((size_t)b * NCHUNK + c) * 8 + n) * 256 + d] = h[n];
}

// per (b,n): chain over 128 chunks. Loads batched 16-ahead so the dependent
// chain pays L2 latency 8x, not 128x.
__global__ __launch_bounds__(256)
void k_scan2(const float* __restrict__ chS, const float* __restrict__ chB,
             const float* __restrict__ A_log, float* __restrict__ hinit)
{
    const int b = blockIdx.x >> 3;
    const int n = blockIdx.x & 7;
    const int d = threadIdx.x;
    const float a = -__expf(A_log[d * 8 + n]);
    float h = 0.0f;
    for (int cb = 0; cb < NCHUNK; cb += 16) {
        float S[16], Bc[16];
#pragma unroll
        for (int j = 0; j < 16; ++j) {
            S[j]  = chS[((size_t)b * NCHUNK + cb + j) * 256 + d];
            Bc[j] = chB[(((size_t)b * NCHUNK + cb + j) * 8 + n) * 256 + d];
        }
#pragma unroll
        for (int j = 0; j < 16; ++j) {
            hinit[(((size_t)b * NCHUNK + cb + j) * 8 + n) * 256 + d] = h;
            h = __expf(a * S[j]) * h + Bc[j];
        }
    }
}

__global__ __launch_bounds__(256)
void k_scan3(const float* __restrict__ delta_t, const float* __restrict__ u_t,
             const float* __restrict__ xdbl, const float* __restrict__ A_log,
             const float* __restrict__ Dp, const float* __restrict__ hinit,
             unsigned short* __restrict__ ybh, unsigned short* __restrict__ ybl)
{
    __shared__ float Bsh[8][CLEN];
    __shared__ float Csh[8][CLEN];
    const int b = blockIdx.x >> 7;
    const int c = blockIdx.x & 127;
    const int d = threadIdx.x;
    const int l0 = c * CLEN;
    {
        int s = threadIdx.x;
        int i = s >> 3, n = s & 7;
        size_t row = ((size_t)b * 4096 + l0 + i) * 48;
        Bsh[n][i] = xdbl[row + 32 + n];
        Csh[n][i] = xdbl[row + 40 + n];
    }
    float a[8], h[8];
#pragma unroll
    for (int n = 0; n < 8; ++n) {
        a[n] = -__expf(A_log[d * 8 + n]);
        h[n] = hinit[(((size_t)b * NCHUNK + c) * 8 + n) * 256 + d];
    }
    const float Dd = Dp[d];
    __syncthreads();
    const float* dp = delta_t + ((size_t)b * 4096 + l0) * 256 + d;
    const float* up = u_t     + ((size_t)b * 4096 + l0) * 256 + d;
    for (int i = 0; i < CLEN; ++i) {
        float dlt = dp[(size_t)i * 256];
        float u   = up[(size_t)i * 256];
        float du  = dlt * u;
        float y   = u * Dd;
#pragma unroll
        for (int n = 0; n < 8; ++n) {
            float dA = __expf(dlt * a[n]);
            h[n] = dA * h[n] + du * Bsh[n][i];
            y += h[n] * Csh[n][i];
        }
        int l = l0 + i;
        size_t oidx = (b < 2) ? ((size_t)b * 4096 + l) * 1024 + d
                              : ((size_t)(b - 2) * 4096 + (4095 - l)) * 1024 + 512 + d;
        unsigned short hh = f2bf(y);
        ybh[oidx] = hh;
        ybl[oidx] = f2bf(y - bf2f(hh));
    }
}

// ============================================================================
extern "C" void kernel_launch(void* const* d_in, const int* in_sizes, int n_in,
                              void* d_out, int out_size, void* d_ws, size_t ws_size,
                              hipStream_t stream)
{
    const float* hs    = (const float*)d_in[0];   // (2,4096,512)
    const float* w_in  = (const float*)d_in[1];   // (1024,512)
    const float* w_xp  = (const float*)d_in[2];   // (48,256)
    const float* w_dt  = (const float*)d_in[3];   // (256,32)
    const float* b_dt  = (const float*)d_in[4];   // (256,)
    const float* A_log = (const float*)d_in[5];   // (256,8)
    const float* Dpar  = (const float*)d_in[6];   // (256,)
    const float* w_cx  = (const float*)d_in[7];   // (256,1,4)
    const float* w_cz  = (const float*)d_in[8];   // (256,1,4)
    const float* w_out = (const float*)d_in[9];   // (512,1024)
    float* out = (float*)d_out;                   // (2,4096,512)

    float* ws = (float*)d_ws;
    const size_t NX = (size_t)4 * 4096 * 256;       // 4,194,304 floats
    float* x_t  = ws;                               // [4][4096][256] fp32 (dead after conv_x)
    float* z_t  = ws + NX;                          // [4][4096][256] fp32
    float* u_t  = ws + 2 * NX;                      // [4][4096][256] fp32
    float* dlt  = ws + 3 * NX;                      // [4][4096][256] fp32
    float* xdbl = ws + 4 * NX;                      // [4][4096][48]
    float* chS  = xdbl + 786432;                    // [4][128][256]
    float* chB  = chS + 131072;                     // [4][128][8][256]
    float* hin  = chB + 1048576;                    // [4][128][8][256]
    unsigned short* hsh = (unsigned short*)(hin + 1048576);  // [8192][512] bf16 (dead after in_proj)
    unsigned short* hsl = hsh + 4194304;                     // [8192][512] bf16 (dead after in_proj)
    unsigned short* wih = hsl + 4194304;            // [1024][512] bf16
    unsigned short* wil = wih + 524288;
    unsigned short* woh = wil + 524288;             // [512][1024] bf16
    unsigned short* wol = woh + 524288;
    // aliases (stream order makes these safe):
    unsigned short* ybh = (unsigned short*)x_t;     // [2][4096][1024] bf16  (over dead x_t)
    unsigned short* ybl = hsh;                      // [2][4096][1024] bf16  (over dead hs hi/lo)

    k_cast_all     <<<5120,         256, 0, stream>>>(hs, hsh, hsl, w_in, wih, wil, w_out, woh, wol);
    k_in_proj_mfma <<<dim3(16, 64), 256, 0, stream>>>(hsh, hsl, wih, wil, x_t, z_t);
    k_conv_x4      <<<4096,         256, 0, stream>>>(x_t, w_cx, u_t);
    k_conv_z4      <<<4096,         256, 0, stream>>>(z_t, w_cz, ybh, ybl);
    k_xproj        <<<128,          256, 0, stream>>>(u_t, w_xp, xdbl);
    k_dtproj       <<<dim3(256, 2), 256, 0, stream>>>(xdbl, w_dt, b_dt, dlt);
    k_scan1        <<<512,          256, 0, stream>>>(dlt, u_t, xdbl, A_log, chS, chB);
    k_scan2        <<<32,           256, 0, stream>>>(chS, chB, A_log, hin);
    k_scan3        <<<512,          256, 0, stream>>>(dlt, u_t, xdbl, A_log, Dpar, hin, ybh, ybl);
    k_out_proj_mfma<<<dim3(8, 64),  256, 0, stream>>>(ybh, ybl, woh, wol, out);
}

// Round 4
// 281.917 us; speedup vs baseline: 1.6748x; 1.0478x over previous
//
#include <hip/hip_runtime.h>
#include <math.h>

// Problem constants
#define LSEQ   4096
#define DHALF  256
#define NSTATE 8
#define NCHUNK 128           // scan chunks
#define CLEN   32            // chunk length (NCHUNK*CLEN = 4096)

typedef __attribute__((ext_vector_type(8))) short short8;   // 8 x bf16 fragment
typedef __attribute__((ext_vector_type(4))) float f32x4;
typedef __attribute__((ext_vector_type(4))) unsigned short us4;

__device__ __forceinline__ float silu_f(float v)     { return v / (1.0f + __expf(-v)); }
__device__ __forceinline__ float softplus_f(float v) { return v > 20.0f ? v : log1pf(__expf(v)); }

__device__ __forceinline__ unsigned short f2bf(float f) {
    unsigned int u = __float_as_uint(f);
    return (unsigned short)((u + 0x7fffu + ((u >> 16) & 1u)) >> 16);
}
__device__ __forceinline__ float bf2f(unsigned short h) {
    return __uint_as_float(((unsigned int)h) << 16);
}

// async global->LDS, 16B per lane; LDS dest = wave-uniform base + lane*16
__device__ __forceinline__ void gload16(const void* g, void* l) {
    __builtin_amdgcn_global_load_lds((const __attribute__((address_space(1))) void*)g,
                                     (__attribute__((address_space(3))) void*)l, 16, 0, 0);
}

// ============================================================================
// fp32 -> bf16 hi/lo split cast, all 3 tensors in one launch.
// seg0: hs (n4=1048576), seg1: w_in (131072), seg2: w_out (131072)
// ============================================================================
__global__ __launch_bounds__(256)
void k_cast_all(const float* __restrict__ s0, unsigned short* __restrict__ h0, unsigned short* __restrict__ l0,
                const float* __restrict__ s1, unsigned short* __restrict__ h1, unsigned short* __restrict__ l1,
                const float* __restrict__ s2, unsigned short* __restrict__ h2, unsigned short* __restrict__ l2)
{
    int i = blockIdx.x * 256 + threadIdx.x;
    const float* src; unsigned short* hi; unsigned short* lo; int off;
    if (i < 1048576)      { src = s0; hi = h0; lo = l0; off = i; }
    else if (i < 1179648) { src = s1; hi = h1; lo = l1; off = i - 1048576; }
    else                  { src = s2; hi = h2; lo = l2; off = i - 1179648; }
    float4 v = ((const float4*)src)[off];
    us4 h, l;
    h.x = f2bf(v.x); l.x = f2bf(v.x - bf2f(h.x));
    h.y = f2bf(v.y); l.y = f2bf(v.y - bf2f(h.y));
    h.z = f2bf(v.z); l.z = f2bf(v.z - bf2f(h.z));
    h.w = f2bf(v.w); l.w = f2bf(v.w - bf2f(h.w));
    ((us4*)hi)[off] = h;
    ((us4*)lo)[off] = l;
}

// ============================================================================
// MFMA bt-GEMM core (C = A * B^T), bf16 hi/lo split (3 products).
// 128(M) x 64(N) tile / block, 4 waves each 64x32 via 4x2 16x16x32 MFMAs.
// LDS 16B chunks XOR-swizzled by ((row>>1)&3): 2-way bank alias = free.
// Swizzle applied on the per-lane GLOBAL address (LDS dst stays
// wave-uniform base + lane*16 per the global_load_lds constraint).
// ============================================================================
#define GEMM_CORE64(K_)                                                                 \
    const int t = threadIdx.x;                                                          \
    const int wv = t >> 6, lane = t & 63;                                               \
    const int wm = (wv & 1) * 64, wn = (wv >> 1) * 32;                                  \
    const int lm = lane & 15, q = lane >> 4;                                            \
    const int M0 = blockIdx.y * 128, N0 = blockIdx.x * 64;                              \
    const int slot = lane & 3;                                                          \
    const int rA1 = wv * 32 + (lane >> 2);                                              \
    const int rA2 = rA1 + 16;                                                           \
    const int rB  = wv * 16 + (lane >> 2);                                              \
    const int cA1 = slot ^ ((rA1 >> 1) & 3);                                            \
    const int cA2 = slot ^ ((rA2 >> 1) & 3);                                            \
    const int cB  = slot ^ ((rB  >> 1) & 3);                                            \
    const int lbA1 = wv * 1024, lbA2 = lbA1 + 512;   /* ushort idx, wave-uniform */     \
    const int lbB  = wv * 512;                                                          \
    const int pq = (q ^ ((lm >> 1) & 3)) * 8;                                           \
    const size_t gA1 = (size_t)(M0 + rA1) * K_ + cA1 * 8;                               \
    const size_t gA2 = (size_t)(M0 + rA2) * K_ + cA2 * 8;                               \
    const size_t gB1 = (size_t)(N0 + rB ) * K_ + cB  * 8;                               \
    f32x4 acc[4][2] = {};                                                               \
    for (int kb = 0; kb < K_; kb += 32) {                                               \
        __syncthreads();                                                                \
        gload16(Ah + gA1 + kb, &sAh[lbA1]);                                             \
        gload16(Ah + gA2 + kb, &sAh[lbA2]);                                             \
        gload16(Al + gA1 + kb, &sAl[lbA1]);                                             \
        gload16(Al + gA2 + kb, &sAl[lbA2]);                                             \
        gload16(Bh + gB1 + kb, &sBh[lbB]);                                              \
        gload16(Bl + gB1 + kb, &sBl[lbB]);                                              \
        __syncthreads();                                                                \
        short8 ah[4], al[4], bh[2], bl[2];                                              \
        _Pragma("unroll")                                                               \
        for (int i = 0; i < 4; ++i) {                                                   \
            ah[i] = *(const short8*)&sAh[(wm + i * 16 + lm) * 32 + pq];                 \
            al[i] = *(const short8*)&sAl[(wm + i * 16 + lm) * 32 + pq];                 \
        }                                                                               \
        _Pragma("unroll")                                                               \
        for (int j = 0; j < 2; ++j) {                                                   \
            bh[j] = *(const short8*)&sBh[(wn + j * 16 + lm) * 32 + pq];                 \
            bl[j] = *(const short8*)&sBl[(wn + j * 16 + lm) * 32 + pq];                 \
        }                                                                               \
        _Pragma("unroll")                                                               \
        for (int i = 0; i < 4; ++i)                                                     \
            _Pragma("unroll")                                                           \
            for (int j = 0; j < 2; ++j)                                                 \
                acc[i][j] = __builtin_amdgcn_mfma_f32_16x16x32_bf16(ah[i], bh[j], acc[i][j], 0, 0, 0); \
        _Pragma("unroll")                                                               \
        for (int i = 0; i < 4; ++i)                                                     \
            _Pragma("unroll")                                                           \
            for (int j = 0; j < 2; ++j)                                                 \
                acc[i][j] = __builtin_amdgcn_mfma_f32_16x16x32_bf16(ah[i], bl[j], acc[i][j], 0, 0, 0); \
        _Pragma("unroll")                                                               \
        for (int i = 0; i < 4; ++i)                                                     \
            _Pragma("unroll")                                                           \
            for (int j = 0; j < 2; ++j)                                                 \
                acc[i][j] = __builtin_amdgcn_mfma_f32_16x16x32_bf16(al[i], bh[j], acc[i][j], 0, 0, 0); \
    }

// in_proj: M=8192 (b,l), N=1024 (e), K=512. Epilogue scatter folds direction
// split + reverse. grid (16,64) = 1024 blocks = 4/CU.
__global__ __launch_bounds__(256)
void k_in_proj_mfma(const unsigned short* __restrict__ Ah, const unsigned short* __restrict__ Al,
                    const unsigned short* __restrict__ Bh, const unsigned short* __restrict__ Bl,
                    float* __restrict__ x_t, float* __restrict__ z_t)
{
    __shared__ unsigned short sAh[128 * 32], sAl[128 * 32], sBh[64 * 32], sBl[64 * 32];
    GEMM_CORE64(512)
    const int region = N0 >> 8;               // 0..3 uniform per block (64 | 256)
    const int eobase = (N0 & 255) + wn;
    float* base = ((region & 1) == 0) ? x_t : z_t;
#pragma unroll
    for (int i = 0; i < 4; ++i) {
#pragma unroll
        for (int r = 0; r < 4; ++r) {
            int m = M0 + wm + i * 16 + q * 4 + r;
            int b = m >> 12, l = m & 4095;
            size_t rowoff = (region < 2)
                ? ((size_t)b * 4096 + l) * 256
                : ((size_t)(b + 2) * 4096 + (4095 - l)) * 256;
#pragma unroll
            for (int j = 0; j < 2; ++j)
                base[rowoff + eobase + j * 16 + lm] = acc[i][j][r];
        }
    }
}

// out_proj: M=8192 (b,l), N=512 (o), K=1024. grid (8,64) = 512 blocks = 2/CU.
__global__ __launch_bounds__(256)
void k_out_proj_mfma(const unsigned short* __restrict__ Ah, const unsigned short* __restrict__ Al,
                     const unsigned short* __restrict__ Bh, const unsigned short* __restrict__ Bl,
                     float* __restrict__ out)
{
    __shared__ unsigned short sAh[128 * 32], sAl[128 * 32], sBh[64 * 32], sBl[64 * 32];
    GEMM_CORE64(1024)
#pragma unroll
    for (int i = 0; i < 4; ++i) {
#pragma unroll
        for (int r = 0; r < 4; ++r) {
            size_t m = (size_t)(M0 + wm + i * 16 + q * 4 + r);
#pragma unroll
            for (int j = 0; j < 2; ++j)
                out[m * 512 + N0 + wn + j * 16 + lm] = acc[i][j][r];
        }
    }
}

// ============================================================================
// conv_x: dilated (8) causal depthwise conv + SiLU, float4 over channels.
// 1,048,576 threads; thread -> (b, l, d0=4*g). x_t -> u_t [4][4096][256]
// ============================================================================
__global__ __launch_bounds__(256)
void k_conv_x4(const float* __restrict__ x_t, const float* __restrict__ w,
               float* __restrict__ u_t)
{
    int idx = blockIdx.x * 256 + threadIdx.x;
    int b = idx >> 18, rem = idx & 262143;
    int l = rem >> 6, d0 = (rem & 63) * 4;
    const float* base = x_t + (size_t)b * 4096 * 256 + d0;
    float4 wv0 = *(const float4*)(w + (d0 + 0) * 4);
    float4 wv1 = *(const float4*)(w + (d0 + 1) * 4);
    float4 wv2 = *(const float4*)(w + (d0 + 2) * 4);
    float4 wv3 = *(const float4*)(w + (d0 + 3) * 4);
    float4 tp = *(const float4*)(base + (size_t)l * 256);
    float4 a = make_float4(wv0.w * tp.x, wv1.w * tp.y, wv2.w * tp.z, wv3.w * tp.w);
    if (l >= 8) {
        tp = *(const float4*)(base + (size_t)(l - 8) * 256);
        a.x += wv0.z * tp.x; a.y += wv1.z * tp.y; a.z += wv2.z * tp.z; a.w += wv3.z * tp.w;
    }
    if (l >= 16) {
        tp = *(const float4*)(base + (size_t)(l - 16) * 256);
        a.x += wv0.y * tp.x; a.y += wv1.y * tp.y; a.z += wv2.y * tp.z; a.w += wv3.y * tp.w;
    }
    if (l >= 24) {
        tp = *(const float4*)(base + (size_t)(l - 24) * 256);
        a.x += wv0.x * tp.x; a.y += wv1.x * tp.y; a.z += wv2.x * tp.z; a.w += wv3.x * tp.w;
    }
    float4 o = make_float4(silu_f(a.x), silu_f(a.y), silu_f(a.z), silu_f(a.w));
    *(float4*)(u_t + ((size_t)b * 4096 + l) * 256 + d0) = o;
}

// ============================================================================
// conv_z: dilation-1 causal conv + SiLU -> ybuf z-channels as bf16 hi/lo,
// direction un-reversal folded in. ybuf: [2][4096][1024]
// ============================================================================
__global__ __launch_bounds__(256)
void k_conv_z4(const float* __restrict__ z_t, const float* __restrict__ w,
               unsigned short* __restrict__ ybh, unsigned short* __restrict__ ybl)
{
    int idx = blockIdx.x * 256 + threadIdx.x;
    int b = idx >> 18, rem = idx & 262143;
    int l = rem >> 6, d0 = (rem & 63) * 4;
    const float* base = z_t + (size_t)b * 4096 * 256 + d0;
    float4 wv0 = *(const float4*)(w + (d0 + 0) * 4);
    float4 wv1 = *(const float4*)(w + (d0 + 1) * 4);
    float4 wv2 = *(const float4*)(w + (d0 + 2) * 4);
    float4 wv3 = *(const float4*)(w + (d0 + 3) * 4);
    float4 tp = *(const float4*)(base + (size_t)l * 256);
    float4 a = make_float4(wv0.w * tp.x, wv1.w * tp.y, wv2.w * tp.z, wv3.w * tp.w);
    if (l >= 1) {
        tp = *(const float4*)(base + (size_t)(l - 1) * 256);
        a.x += wv0.z * tp.x; a.y += wv1.z * tp.y; a.z += wv2.z * tp.z; a.w += wv3.z * tp.w;
    }
    if (l >= 2) {
        tp = *(const float4*)(base + (size_t)(l - 2) * 256);
        a.x += wv0.y * tp.x; a.y += wv1.y * tp.y; a.z += wv2.y * tp.z; a.w += wv3.y * tp.w;
    }
    if (l >= 3) {
        tp = *(const float4*)(base + (size_t)(l - 3) * 256);
        a.x += wv0.x * tp.x; a.y += wv1.x * tp.y; a.z += wv2.x * tp.z; a.w += wv3.x * tp.w;
    }
    float v0 = silu_f(a.x), v1 = silu_f(a.y), v2 = silu_f(a.z), v3 = silu_f(a.w);
    size_t oidx = (b < 2) ? ((size_t)b * 4096 + l) * 1024 + 256 + d0
                          : ((size_t)(b - 2) * 4096 + (4095 - l)) * 1024 + 768 + d0;
    us4 h, lo;
    h.x = f2bf(v0); lo.x = f2bf(v0 - bf2f(h.x));
    h.y = f2bf(v1); lo.y = f2bf(v1 - bf2f(h.y));
    h.z = f2bf(v2); lo.z = f2bf(v2 - bf2f(h.z));
    h.w = f2bf(v3); lo.w = f2bf(v3 - bf2f(h.w));
    *(us4*)(ybh + oidx) = h;
    *(us4*)(ybl + oidx) = lo;
}

// ============================================================================
// x_proj: xdbl[m][e] = sum_d u_t[m][d] * Wx[e][d];  M=16384, N=48, K=256
// ============================================================================
__global__ __launch_bounds__(256)
void k_xproj(const float* __restrict__ U, const float* __restrict__ W,
             float* __restrict__ xdbl)
{
    __shared__ float As[32][132];
    __shared__ float Bs[32][52];
    const int t = threadIdx.x;
    const int m0 = blockIdx.x * 128;
    const int lrow = t >> 1;
    const int lk0  = (t & 1) * 16;
    const int tx = t & 15, ty = t >> 4;
    const int be = t >> 2;
    const int bk = (t & 3) * 8;
    float acc[8][3];
#pragma unroll
    for (int i = 0; i < 8; ++i) { acc[i][0] = 0.f; acc[i][1] = 0.f; acc[i][2] = 0.f; }

    for (int kb = 0; kb < 256; kb += 32) {
        const float* ap = U + ((size_t)(m0 + lrow)) * 256 + kb + lk0;
        float4 a0 = *(const float4*)(ap);
        float4 a1 = *(const float4*)(ap + 4);
        float4 a2 = *(const float4*)(ap + 8);
        float4 a3 = *(const float4*)(ap + 12);
        float4 b0, b1;
        if (be < 48) {
            const float* bp = W + (size_t)be * 256 + kb + bk;
            b0 = *(const float4*)(bp);
            b1 = *(const float4*)(bp + 4);
        }
        __syncthreads();
        As[lk0+ 0][lrow] = a0.x; As[lk0+ 1][lrow] = a0.y; As[lk0+ 2][lrow] = a0.z; As[lk0+ 3][lrow] = a0.w;
        As[lk0+ 4][lrow] = a1.x; As[lk0+ 5][lrow] = a1.y; As[lk0+ 6][lrow] = a1.z; As[lk0+ 7][lrow] = a1.w;
        As[lk0+ 8][lrow] = a2.x; As[lk0+ 9][lrow] = a2.y; As[lk0+10][lrow] = a2.z; As[lk0+11][lrow] = a2.w;
        As[lk0+12][lrow] = a3.x; As[lk0+13][lrow] = a3.y; As[lk0+14][lrow] = a3.z; As[lk0+15][lrow] = a3.w;
        if (be < 48) {
            Bs[bk+0][be] = b0.x; Bs[bk+1][be] = b0.y; Bs[bk+2][be] = b0.z; Bs[bk+3][be] = b0.w;
            Bs[bk+4][be] = b1.x; Bs[bk+5][be] = b1.y; Bs[bk+6][be] = b1.z; Bs[bk+7][be] = b1.w;
        }
        __syncthreads();
#pragma unroll
        for (int k = 0; k < 32; ++k) {
            float4 av0 = *(const float4*)&As[k][ty*8];
            float4 av1 = *(const float4*)&As[k][ty*8+4];
            float av[8] = {av0.x,av0.y,av0.z,av0.w,av1.x,av1.y,av1.z,av1.w};
            float bva = Bs[k][tx*3+0];
            float bvb = Bs[k][tx*3+1];
            float bvc = Bs[k][tx*3+2];
#pragma unroll
            for (int i = 0; i < 8; ++i) {
                acc[i][0] = fmaf(av[i], bva, acc[i][0]);
                acc[i][1] = fmaf(av[i], bvb, acc[i][1]);
                acc[i][2] = fmaf(av[i], bvc, acc[i][2]);
            }
        }
    }
#pragma unroll
    for (int i = 0; i < 8; ++i) {
        size_t row = (size_t)(m0 + ty * 8 + i) * 48 + tx * 3;
        xdbl[row + 0] = acc[i][0];
        xdbl[row + 1] = acc[i][1];
        xdbl[row + 2] = acc[i][2];
    }
}

// ============================================================================
// dt_proj + softplus:  delta[m][d] = softplus(dot(xdbl[m][0:32], Wdt[d]) + b[d])
// Thread = channel d (coalesced store); 32 m-rows per block; W row in regs;
// dtr tile in LDS, read via same-address broadcast ds_read_b128 (conflict-free).
// 512 blocks, ~60 VGPR -> high occupancy; replaces the 252-VGPR spilling version.
// ============================================================================
__global__ __launch_bounds__(256)
void k_dtproj(const float* __restrict__ xdbl, const float* __restrict__ Wdt,
              const float* __restrict__ bdt, float* __restrict__ delta_t)
{
    __shared__ float Xs[32][32];
    const int t  = threadIdx.x;            // d = t
    const int m0 = blockIdx.x * 32;
    {   // stage dtr[m0..m0+32][0..32]: 256 threads x float4
        int r = t >> 3;
        int c = (t & 7) * 4;
        *(float4*)&Xs[r][c] = *(const float4*)(xdbl + (size_t)(m0 + r) * 48 + c);
    }
    float w[32];
    {
        const float4* wp = (const float4*)(Wdt + t * 32);
#pragma unroll
        for (int j = 0; j < 8; ++j) {
            float4 v = wp[j];
            w[4*j+0] = v.x; w[4*j+1] = v.y; w[4*j+2] = v.z; w[4*j+3] = v.w;
        }
    }
    const float bias = bdt[t];
    __syncthreads();
    for (int m = 0; m < 32; ++m) {
        const float4* xr = (const float4*)&Xs[m][0];
        float acc = bias;
#pragma unroll
        for (int j = 0; j < 8; ++j) {
            float4 xv = xr[j];
            acc = fmaf(xv.x, w[4*j+0], acc);
            acc = fmaf(xv.y, w[4*j+1], acc);
            acc = fmaf(xv.z, w[4*j+2], acc);
            acc = fmaf(xv.w, w[4*j+3], acc);
        }
        delta_t[(size_t)(m0 + m) * 256 + t] = softplus_f(acc);
    }
}

// ============================================================================
// Selective scan, chunked (NCHUNK=128 chunks x CLEN=32 steps).
// ============================================================================
__global__ __launch_bounds__(256)
void k_scan1(const float* __restrict__ delta_t, const float* __restrict__ u_t,
             const float* __restrict__ xdbl, const float* __restrict__ A_log,
             float* __restrict__ chS, float* __restrict__ chB)
{
    __shared__ float Bsh[8][CLEN];
    const int b = blockIdx.x >> 7;
    const int c = blockIdx.x & 127;
    const int d = threadIdx.x;
    const int l0 = c * CLEN;
    {
        int s = threadIdx.x;   // 256 = 8*32 exactly
        int i = s >> 3, n = s & 7;
        Bsh[n][i] = xdbl[((size_t)b * 4096 + l0 + i) * 48 + 32 + n];
    }
    float a[8];
#pragma unroll
    for (int n = 0; n < 8; ++n) a[n] = -__expf(A_log[d * 8 + n]);
    float h[8];
#pragma unroll
    for (int n = 0; n < 8; ++n) h[n] = 0.0f;
    float S = 0.0f;
    __syncthreads();
    const float* dp = delta_t + ((size_t)b * 4096 + l0) * 256 + d;
    const float* up = u_t     + ((size_t)b * 4096 + l0) * 256 + d;
    for (int i = 0; i < CLEN; ++i) {
        float dlt = dp[(size_t)i * 256];
        float u   = up[(size_t)i * 256];
        float du  = dlt * u;
        S += dlt;
#pragma unroll
        for (int n = 0; n < 8; ++n) {
            float dA = __expf(dlt * a[n]);
            h[n] = dA * h[n] + du * Bsh[n][i];
        }
    }
    chS[((size_t)b * NCHUNK + c) * 256 + d] = S;
#pragma unroll
    for (int n = 0; n < 8; ++n)
        chB[(((size_t)b * NCHUNK + c) * 8 + n) * 256 + d] = h[n];
}

// per (b,n): chain over 128 chunks. Loads batched 16-ahead so the dependent
// chain pays L2 latency 8x, not 128x.
__global__ __launch_bounds__(256)
void k_scan2(const float* __restrict__ chS, const float* __restrict__ chB,
             const float* __restrict__ A_log, float* __restrict__ hinit)
{
    const int b = blockIdx.x >> 3;
    const int n = blockIdx.x & 7;
    const int d = threadIdx.x;
    const float a = -__expf(A_log[d * 8 + n]);
    float h = 0.0f;
    for (int cb = 0; cb < NCHUNK; cb += 16) {
        float S[16], Bc[16];
#pragma unroll
        for (int j = 0; j < 16; ++j) {
            S[j]  = chS[((size_t)b * NCHUNK + cb + j) * 256 + d];
            Bc[j] = chB[(((size_t)b * NCHUNK + cb + j) * 8 + n) * 256 + d];
        }
#pragma unroll
        for (int j = 0; j < 16; ++j) {
            hinit[(((size_t)b * NCHUNK + cb + j) * 8 + n) * 256 + d] = h;
            h = __expf(a * S[j]) * h + Bc[j];
        }
    }
}

__global__ __launch_bounds__(256)
void k_scan3(const float* __restrict__ delta_t, const float* __restrict__ u_t,
             const float* __restrict__ xdbl, const float* __restrict__ A_log,
             const float* __restrict__ Dp, const float* __restrict__ hinit,
             unsigned short* __restrict__ ybh, unsigned short* __restrict__ ybl)
{
    __shared__ float Bsh[8][CLEN];
    __shared__ float Csh[8][CLEN];
    const int b = blockIdx.x >> 7;
    const int c = blockIdx.x & 127;
    const int d = threadIdx.x;
    const int l0 = c * CLEN;
    {
        int s = threadIdx.x;
        int i = s >> 3, n = s & 7;
        size_t row = ((size_t)b * 4096 + l0 + i) * 48;
        Bsh[n][i] = xdbl[row + 32 + n];
        Csh[n][i] = xdbl[row + 40 + n];
    }
    float a[8], h[8];
#pragma unroll
    for (int n = 0; n < 8; ++n) {
        a[n] = -__expf(A_log[d * 8 + n]);
        h[n] = hinit[(((size_t)b * NCHUNK + c) * 8 + n) * 256 + d];
    }
    const float Dd = Dp[d];
    __syncthreads();
    const float* dp = delta_t + ((size_t)b * 4096 + l0) * 256 + d;
    const float* up = u_t     + ((size_t)b * 4096 + l0) * 256 + d;
    for (int i = 0; i < CLEN; ++i) {
        float dlt = dp[(size_t)i * 256];
        float u   = up[(size_t)i * 256];
        float du  = dlt * u;
        float y   = u * Dd;
#pragma unroll
        for (int n = 0; n < 8; ++n) {
            float dA = __expf(dlt * a[n]);
            h[n] = dA * h[n] + du * Bsh[n][i];
            y += h[n] * Csh[n][i];
        }
        int l = l0 + i;
        size_t oidx = (b < 2) ? ((size_t)b * 4096 + l) * 1024 + d
                              : ((size_t)(b - 2) * 4096 + (4095 - l)) * 1024 + 512 + d;
        unsigned short hh = f2bf(y);
        ybh[oidx] = hh;
        ybl[oidx] = f2bf(y - bf2f(hh));
    }
}

// ============================================================================
extern "C" void kernel_launch(void* const* d_in, const int* in_sizes, int n_in,
                              void* d_out, int out_size, void* d_ws, size_t ws_size,
                              hipStream_t stream)
{
    const float* hs    = (const float*)d_in[0];   // (2,4096,512)
    const float* w_in  = (const float*)d_in[1];   // (1024,512)
    const float* w_xp  = (const float*)d_in[2];   // (48,256)
    const float* w_dt  = (const float*)d_in[3];   // (256,32)
    const float* b_dt  = (const float*)d_in[4];   // (256,)
    const float* A_log = (const float*)d_in[5];   // (256,8)
    const float* Dpar  = (const float*)d_in[6];   // (256,)
    const float* w_cx  = (const float*)d_in[7];   // (256,1,4)
    const float* w_cz  = (const float*)d_in[8];   // (256,1,4)
    const float* w_out = (const float*)d_in[9];   // (512,1024)
    float* out = (float*)d_out;                   // (2,4096,512)

    float* ws = (float*)d_ws;
    const size_t NX = (size_t)4 * 4096 * 256;       // 4,194,304 floats
    float* x_t  = ws;                               // [4][4096][256] fp32 (dead after conv_x)
    float* z_t  = ws + NX;                          // [4][4096][256] fp32
    float* u_t  = ws + 2 * NX;                      // [4][4096][256] fp32
    float* dlt  = ws + 3 * NX;                      // [4][4096][256] fp32
    float* xdbl = ws + 4 * NX;                      // [4][4096][48]
    float* chS  = xdbl + 786432;                    // [4][128][256]
    float* chB  = chS + 131072;                     // [4][128][8][256]
    float* hin  = chB + 1048576;                    // [4][128][8][256]
    unsigned short* hsh = (unsigned short*)(hin + 1048576);  // [8192][512] bf16 (dead after in_proj)
    unsigned short* hsl = hsh + 4194304;                     // [8192][512] bf16 (dead after in_proj)
    unsigned short* wih = hsl + 4194304;            // [1024][512] bf16
    unsigned short* wil = wih + 524288;
    unsigned short* woh = wil + 524288;             // [512][1024] bf16
    unsigned short* wol = woh + 524288;
    // aliases (stream order makes these safe):
    unsigned short* ybh = (unsigned short*)x_t;     // [2][4096][1024] bf16  (over dead x_t)
    unsigned short* ybl = hsh;                      // [2][4096][1024] bf16  (over dead hs hi/lo)

    k_cast_all     <<<5120,         256, 0, stream>>>(hs, hsh, hsl, w_in, wih, wil, w_out, woh, wol);
    k_in_proj_mfma <<<dim3(16, 64), 256, 0, stream>>>(hsh, hsl, wih, wil, x_t, z_t);
    k_conv_x4      <<<4096,         256, 0, stream>>>(x_t, w_cx, u_t);
    k_conv_z4      <<<4096,         256, 0, stream>>>(z_t, w_cz, ybh, ybl);
    k_xproj        <<<128,          256, 0, stream>>>(u_t, w_xp, xdbl);
    k_dtproj       <<<512,          256, 0, stream>>>(xdbl, w_dt, b_dt, dlt);
    k_scan1        <<<512,          256, 0, stream>>>(dlt, u_t, xdbl, A_log, chS, chB);
    k_scan2        <<<32,           256, 0, stream>>>(chS, chB, A_log, hin);
    k_scan3        <<<512,          256, 0, stream>>>(dlt, u_t, xdbl, A_log, Dpar, hin, ybh, ybl);
    k_out_proj_mfma<<<dim3(8, 64),  256, 0, stream>>>(ybh, ybl, woh, wol, out);
}

// Round 5
// 246.320 us; speedup vs baseline: 1.9168x; 1.1445x over previous
//
#include <hip/hip_runtime.h>
#include <math.h>

// Problem constants
#define LSEQ   4096
#define DHALF  256
#define NSTATE 8
#define NCHUNK 256           // scan chunks
#define CLEN   16            // chunk length (NCHUNK*CLEN = 4096)

typedef __attribute__((ext_vector_type(8))) _Float16 half8;   // MFMA f16 A/B frag
typedef __attribute__((ext_vector_type(4))) _Float16 half4v;
typedef __attribute__((ext_vector_type(4))) float f32x4;

__device__ __forceinline__ float silu_f(float v)     { return v / (1.0f + __expf(-v)); }
__device__ __forceinline__ float softplus_f(float v) { return v > 20.0f ? v : log1pf(__expf(v)); }

// async global->LDS, 16B per lane; LDS dest = wave-uniform base + lane*16
__device__ __forceinline__ void gload16(const void* g, void* l) {
    __builtin_amdgcn_global_load_lds((const __attribute__((address_space(1))) void*)g,
                                     (__attribute__((address_space(3))) void*)l, 16, 0, 0);
}

// ============================================================================
// fp32 -> fp16 cast, all 3 tensors in one launch.
// seg0: hs (n4=1048576), seg1: w_in (131072), seg2: w_out (131072)
// ============================================================================
__global__ __launch_bounds__(256)
void k_cast_all(const float* __restrict__ s0, _Float16* __restrict__ d0,
                const float* __restrict__ s1, _Float16* __restrict__ d1,
                const float* __restrict__ s2, _Float16* __restrict__ d2)
{
    int i = blockIdx.x * 256 + threadIdx.x;
    const float* src; _Float16* dst; int off;
    if (i < 1048576)      { src = s0; dst = d0; off = i; }
    else if (i < 1179648) { src = s1; dst = d1; off = i - 1048576; }
    else                  { src = s2; dst = d2; off = i - 1179648; }
    float4 v = ((const float4*)src)[off];
    half4v h;
    h.x = (_Float16)v.x; h.y = (_Float16)v.y; h.z = (_Float16)v.z; h.w = (_Float16)v.w;
    ((half4v*)dst)[off] = h;
}

// ============================================================================
// MFMA bt-GEMM core (C = A * B^T), fp16 single-product (fp32 accumulate).
// 128(M) x 64(N) tile / block, 4 waves each 64x32 via 4x2 16x16x32 MFMAs.
// BK=64 (half the barriers of BK=32 at same 24KB LDS).
// LDS rows are 128B (bank-aligned); 16B chunks XOR-swizzled by (row&7) so
// fragment ds_read_b128 is 2-way bank-aliased (free). Swizzle applied on the
// per-lane GLOBAL source chunk (LDS dst must stay uniform base + lane*16).
// ============================================================================
#define GEMM_CORE_F16(K_)                                                               \
    const int t = threadIdx.x;                                                          \
    const int wv = t >> 6, lane = t & 63;                                               \
    const int wm = (wv & 1) * 64, wn = (wv >> 1) * 32;                                  \
    const int lm = lane & 15, q = lane >> 4;                                            \
    const int M0 = blockIdx.y * 128, N0 = blockIdx.x * 64;                              \
    const int lr = lane >> 3;                  /* row within 8-row group */             \
    const int cc = (lane & 7) ^ lr;            /* swizzled source chunk  */             \
    const size_t gA = (size_t)(M0 + wv * 32 + lr) * K_ + cc * 8;                        \
    const size_t gB = (size_t)(N0 + wv * 16 + lr) * K_ + cc * 8;                        \
    f32x4 acc[4][2] = {};                                                               \
    for (int kb = 0; kb < K_; kb += 64) {                                               \
        __syncthreads();                                                                \
        gload16(Af + gA + kb,               &sA[(wv * 32 +  0) * 64]);                  \
        gload16(Af + gA + (size_t)8  * K_ + kb, &sA[(wv * 32 +  8) * 64]);              \
        gload16(Af + gA + (size_t)16 * K_ + kb, &sA[(wv * 32 + 16) * 64]);              \
        gload16(Af + gA + (size_t)24 * K_ + kb, &sA[(wv * 32 + 24) * 64]);              \
        gload16(Bf + gB + kb,               &sB[(wv * 16 +  0) * 64]);                  \
        gload16(Bf + gB + (size_t)8  * K_ + kb, &sB[(wv * 16 +  8) * 64]);              \
        __syncthreads();                                                                \
        _Pragma("unroll")                                                               \
        for (int kk = 0; kk < 2; ++kk) {                                                \
            const int cpos = (((kk << 2) + q) ^ (lm & 7)) * 8;                          \
            half8 a[4], b[2];                                                           \
            _Pragma("unroll")                                                           \
            for (int i = 0; i < 4; ++i)                                                 \
                a[i] = *(const half8*)&sA[(wm + i * 16 + lm) * 64 + cpos];              \
            _Pragma("unroll")                                                           \
            for (int j = 0; j < 2; ++j)                                                 \
                b[j] = *(const half8*)&sB[(wn + j * 16 + lm) * 64 + cpos];              \
            _Pragma("unroll")                                                           \
            for (int i = 0; i < 4; ++i)                                                 \
                _Pragma("unroll")                                                       \
                for (int j = 0; j < 2; ++j)                                             \
                    acc[i][j] = __builtin_amdgcn_mfma_f32_16x16x32_f16(a[i], b[j], acc[i][j], 0, 0, 0); \
        }                                                                               \
    }

// in_proj: M=8192 (b,l), N=1024 (e), K=512. Epilogue scatter folds direction
// split + reverse. grid (16,64) = 1024 blocks = 4/CU.
__global__ __launch_bounds__(256)
void k_in_proj_mfma(const _Float16* __restrict__ Af, const _Float16* __restrict__ Bf,
                    float* __restrict__ x_t, float* __restrict__ z_t)
{
    __shared__ _Float16 sA[128 * 64], sB[64 * 64];
    GEMM_CORE_F16(512)
    const int region = N0 >> 8;               // 0..3 uniform per block
    const int eobase = (N0 & 255) + wn;
    float* base = ((region & 1) == 0) ? x_t : z_t;
#pragma unroll
    for (int i = 0; i < 4; ++i) {
#pragma unroll
        for (int r = 0; r < 4; ++r) {
            int m = M0 + wm + i * 16 + q * 4 + r;
            int b = m >> 12, l = m & 4095;
            size_t rowoff = (region < 2)
                ? ((size_t)b * 4096 + l) * 256
                : ((size_t)(b + 2) * 4096 + (4095 - l)) * 256;
#pragma unroll
            for (int j = 0; j < 2; ++j)
                base[rowoff + eobase + j * 16 + lm] = acc[i][j][r];
        }
    }
}

// out_proj: M=8192 (b,l), N=512 (o), K=1024. grid (8,64) = 512 blocks = 2/CU.
__global__ __launch_bounds__(256)
void k_out_proj_mfma(const _Float16* __restrict__ Af, const _Float16* __restrict__ Bf,
                     float* __restrict__ out)
{
    __shared__ _Float16 sA[128 * 64], sB[64 * 64];
    GEMM_CORE_F16(1024)
#pragma unroll
    for (int i = 0; i < 4; ++i) {
#pragma unroll
        for (int r = 0; r < 4; ++r) {
            size_t m = (size_t)(M0 + wm + i * 16 + q * 4 + r);
#pragma unroll
            for (int j = 0; j < 2; ++j)
                out[m * 512 + N0 + wn + j * 16 + lm] = acc[i][j][r];
        }
    }
}

// ============================================================================
// conv_x: dilated (8) causal depthwise conv + SiLU, float4 over channels.
// ============================================================================
__global__ __launch_bounds__(256)
void k_conv_x4(const float* __restrict__ x_t, const float* __restrict__ w,
               float* __restrict__ u_t)
{
    int idx = blockIdx.x * 256 + threadIdx.x;
    int b = idx >> 18, rem = idx & 262143;
    int l = rem >> 6, d0 = (rem & 63) * 4;
    const float* base = x_t + (size_t)b * 4096 * 256 + d0;
    float4 wv0 = *(const float4*)(w + (d0 + 0) * 4);
    float4 wv1 = *(const float4*)(w + (d0 + 1) * 4);
    float4 wv2 = *(const float4*)(w + (d0 + 2) * 4);
    float4 wv3 = *(const float4*)(w + (d0 + 3) * 4);
    float4 tp = *(const float4*)(base + (size_t)l * 256);
    float4 a = make_float4(wv0.w * tp.x, wv1.w * tp.y, wv2.w * tp.z, wv3.w * tp.w);
    if (l >= 8) {
        tp = *(const float4*)(base + (size_t)(l - 8) * 256);
        a.x += wv0.z * tp.x; a.y += wv1.z * tp.y; a.z += wv2.z * tp.z; a.w += wv3.z * tp.w;
    }
    if (l >= 16) {
        tp = *(const float4*)(base + (size_t)(l - 16) * 256);
        a.x += wv0.y * tp.x; a.y += wv1.y * tp.y; a.z += wv2.y * tp.z; a.w += wv3.y * tp.w;
    }
    if (l >= 24) {
        tp = *(const float4*)(base + (size_t)(l - 24) * 256);
        a.x += wv0.x * tp.x; a.y += wv1.x * tp.y; a.z += wv2.x * tp.z; a.w += wv3.x * tp.w;
    }
    float4 o = make_float4(silu_f(a.x), silu_f(a.y), silu_f(a.z), silu_f(a.w));
    *(float4*)(u_t + ((size_t)b * 4096 + l) * 256 + d0) = o;
}

// ============================================================================
// conv_z: dilation-1 causal conv + SiLU -> ybuf z-channels (fp16),
// direction un-reversal folded in. ybuf: [2][4096][1024] fp16
// ============================================================================
__global__ __launch_bounds__(256)
void k_conv_z4(const float* __restrict__ z_t, const float* __restrict__ w,
               _Float16* __restrict__ yb)
{
    int idx = blockIdx.x * 256 + threadIdx.x;
    int b = idx >> 18, rem = idx & 262143;
    int l = rem >> 6, d0 = (rem & 63) * 4;
    const float* base = z_t + (size_t)b * 4096 * 256 + d0;
    float4 wv0 = *(const float4*)(w + (d0 + 0) * 4);
    float4 wv1 = *(const float4*)(w + (d0 + 1) * 4);
    float4 wv2 = *(const float4*)(w + (d0 + 2) * 4);
    float4 wv3 = *(const float4*)(w + (d0 + 3) * 4);
    float4 tp = *(const float4*)(base + (size_t)l * 256);
    float4 a = make_float4(wv0.w * tp.x, wv1.w * tp.y, wv2.w * tp.z, wv3.w * tp.w);
    if (l >= 1) {
        tp = *(const float4*)(base + (size_t)(l - 1) * 256);
        a.x += wv0.z * tp.x; a.y += wv1.z * tp.y; a.z += wv2.z * tp.z; a.w += wv3.z * tp.w;
    }
    if (l >= 2) {
        tp = *(const float4*)(base + (size_t)(l - 2) * 256);
        a.x += wv0.y * tp.x; a.y += wv1.y * tp.y; a.z += wv2.y * tp.z; a.w += wv3.y * tp.w;
    }
    if (l >= 3) {
        tp = *(const float4*)(base + (size_t)(l - 3) * 256);
        a.x += wv0.x * tp.x; a.y += wv1.x * tp.y; a.z += wv2.x * tp.z; a.w += wv3.x * tp.w;
    }
    size_t oidx = (b < 2) ? ((size_t)b * 4096 + l) * 1024 + 256 + d0
                          : ((size_t)(b - 2) * 4096 + (4095 - l)) * 1024 + 768 + d0;
    half4v h;
    h.x = (_Float16)silu_f(a.x); h.y = (_Float16)silu_f(a.y);
    h.z = (_Float16)silu_f(a.z); h.w = (_Float16)silu_f(a.w);
    *(half4v*)(yb + oidx) = h;
}

// ============================================================================
// x_proj: xdbl[m][e] = sum_d u_t[m][d] * Wx[e][d];  M=16384, N=48, K=256
// 512 blocks of 32 rows (fixes 0.125-waves/SIMD starvation of the old 128-blk
// version). U tile in LDS; W staged per-64-k chunk; all reads broadcast/float4.
// ============================================================================
__global__ __launch_bounds__(256)
void k_xproj(const float* __restrict__ U, const float* __restrict__ W,
             float* __restrict__ xdbl)
{
    __shared__ float Xs[32][260];
    __shared__ float Ws[48][68];
    const int t  = threadIdx.x;
    const int m0 = blockIdx.x * 32;
#pragma unroll
    for (int it = 0; it < 8; ++it) {       // 32x256 = 2048 float4
        int idx = t + 256 * it;
        int row = idx >> 6, c = (idx & 63) * 4;
        *(float4*)&Xs[row][c] = *(const float4*)(U + (size_t)(m0 + row) * 256 + c);
    }
    const int r  = t >> 3;                 // 0..31
    const int j0 = (t & 7) * 6;            // 0..42
    float acc[6] = {};
    for (int kb = 0; kb < 256; kb += 64) {
        __syncthreads();
#pragma unroll
        for (int it = 0; it < 3; ++it) {   // 48x64 = 768 float4
            int idx = t + 256 * it;
            int wr = idx >> 4, wc = (idx & 15) * 4;
            *(float4*)&Ws[wr][wc] = *(const float4*)(W + (size_t)wr * 256 + kb + wc);
        }
        __syncthreads();
#pragma unroll
        for (int k4 = 0; k4 < 16; ++k4) {
            float4 x = *(const float4*)&Xs[r][kb + k4 * 4];
#pragma unroll
            for (int jj = 0; jj < 6; ++jj) {
                float4 wv = *(const float4*)&Ws[j0 + jj][k4 * 4];
                acc[jj] = fmaf(x.x, wv.x, acc[jj]);
                acc[jj] = fmaf(x.y, wv.y, acc[jj]);
                acc[jj] = fmaf(x.z, wv.z, acc[jj]);
                acc[jj] = fmaf(x.w, wv.w, acc[jj]);
            }
        }
    }
    float* dst = xdbl + (size_t)(m0 + r) * 48 + j0;
#pragma unroll
    for (int jj = 0; jj < 6; ++jj) dst[jj] = acc[jj];
}

// ============================================================================
// dt_proj + softplus (broadcast structure, ~60 VGPR)
// ============================================================================
__global__ __launch_bounds__(256)
void k_dtproj(const float* __restrict__ xdbl, const float* __restrict__ Wdt,
              const float* __restrict__ bdt, float* __restrict__ delta_t)
{
    __shared__ float Xs[32][32];
    const int t  = threadIdx.x;            // d = t
    const int m0 = blockIdx.x * 32;
    {
        int r = t >> 3;
        int c = (t & 7) * 4;
        *(float4*)&Xs[r][c] = *(const float4*)(xdbl + (size_t)(m0 + r) * 48 + c);
    }
    float w[32];
    {
        const float4* wp = (const float4*)(Wdt + t * 32);
#pragma unroll
        for (int j = 0; j < 8; ++j) {
            float4 v = wp[j];
            w[4*j+0] = v.x; w[4*j+1] = v.y; w[4*j+2] = v.z; w[4*j+3] = v.w;
        }
    }
    const float bias = bdt[t];
    __syncthreads();
    for (int m = 0; m < 32; ++m) {
        const float4* xr = (const float4*)&Xs[m][0];
        float acc = bias;
#pragma unroll
        for (int j = 0; j < 8; ++j) {
            float4 xv = xr[j];
            acc = fmaf(xv.x, w[4*j+0], acc);
            acc = fmaf(xv.y, w[4*j+1], acc);
            acc = fmaf(xv.z, w[4*j+2], acc);
            acc = fmaf(xv.w, w[4*j+3], acc);
        }
        delta_t[(size_t)(m0 + m) * 256 + t] = softplus_f(acc);
    }
}

// ============================================================================
// Selective scan, chunked (NCHUNK=256 chunks x CLEN=16 steps).
// ============================================================================
__global__ __launch_bounds__(256)
void k_scan1(const float* __restrict__ delta_t, const float* __restrict__ u_t,
             const float* __restrict__ xdbl, const float* __restrict__ A_log,
             float* __restrict__ chS, float* __restrict__ chB)
{
    __shared__ float Bsh[8][CLEN];
    const int b = blockIdx.x >> 8;
    const int c = blockIdx.x & 255;
    const int d = threadIdx.x;
    const int l0 = c * CLEN;
    if (threadIdx.x < 128) {
        int i = threadIdx.x >> 3, n = threadIdx.x & 7;
        Bsh[n][i] = xdbl[((size_t)b * 4096 + l0 + i) * 48 + 32 + n];
    }
    float a[8];
#pragma unroll
    for (int n = 0; n < 8; ++n) a[n] = -__expf(A_log[d * 8 + n]);
    float h[8];
#pragma unroll
    for (int n = 0; n < 8; ++n) h[n] = 0.0f;
    float S = 0.0f;
    __syncthreads();
    const float* dp = delta_t + ((size_t)b * 4096 + l0) * 256 + d;
    const float* up = u_t     + ((size_t)b * 4096 + l0) * 256 + d;
    for (int i = 0; i < CLEN; ++i) {
        float dlt = dp[(size_t)i * 256];
        float u   = up[(size_t)i * 256];
        float du  = dlt * u;
        S += dlt;
#pragma unroll
        for (int n = 0; n < 8; ++n) {
            float dA = __expf(dlt * a[n]);
            h[n] = dA * h[n] + du * Bsh[n][i];
        }
    }
    chS[((size_t)b * NCHUNK + c) * 256 + d] = S;
#pragma unroll
    for (int n = 0; n < 8; ++n)
        chB[(((size_t)b * NCHUNK + c) * 8 + n) * 256 + d] = h[n];
}

// per (b,n): chain over 256 chunks, loads batched 16-ahead.
__global__ __launch_bounds__(256)
void k_scan2(const float* __restrict__ chS, const float* __restrict__ chB,
             const float* __restrict__ A_log, float* __restrict__ hinit)
{
    const int b = blockIdx.x >> 3;
    const int n = blockIdx.x & 7;
    const int d = threadIdx.x;
    const float a = -__expf(A_log[d * 8 + n]);
    float h = 0.0f;
    for (int cb = 0; cb < NCHUNK; cb += 16) {
        float S[16], Bc[16];
#pragma unroll
        for (int j = 0; j < 16; ++j) {
            S[j]  = chS[((size_t)b * NCHUNK + cb + j) * 256 + d];
            Bc[j] = chB[(((size_t)b * NCHUNK + cb + j) * 8 + n) * 256 + d];
        }
#pragma unroll
        for (int j = 0; j < 16; ++j) {
            hinit[(((size_t)b * NCHUNK + cb + j) * 8 + n) * 256 + d] = h;
            h = __expf(a * S[j]) * h + Bc[j];
        }
    }
}

__global__ __launch_bounds__(256)
void k_scan3(const float* __restrict__ delta_t, const float* __restrict__ u_t,
             const float* __restrict__ xdbl, const float* __restrict__ A_log,
             const float* __restrict__ Dp, const float* __restrict__ hinit,
             _Float16* __restrict__ yb)
{
    __shared__ float Bsh[8][CLEN];
    __shared__ float Csh[8][CLEN];
    const int b = blockIdx.x >> 8;
    const int c = blockIdx.x & 255;
    const int d = threadIdx.x;
    const int l0 = c * CLEN;
    {
        int s = threadIdx.x;
        if (s < 128) {
            int i = s >> 3, n = s & 7;
            Bsh[n][i] = xdbl[((size_t)b * 4096 + l0 + i) * 48 + 32 + n];
        } else {
            int s2 = s - 128;
            int i = s2 >> 3, n = s2 & 7;
            Csh[n][i] = xdbl[((size_t)b * 4096 + l0 + i) * 48 + 40 + n];
        }
    }
    float a[8], h[8];
#pragma unroll
    for (int n = 0; n < 8; ++n) {
        a[n] = -__expf(A_log[d * 8 + n]);
        h[n] = hinit[(((size_t)b * NCHUNK + c) * 8 + n) * 256 + d];
    }
    const float Dd = Dp[d];
    __syncthreads();
    const float* dp = delta_t + ((size_t)b * 4096 + l0) * 256 + d;
    const float* up = u_t     + ((size_t)b * 4096 + l0) * 256 + d;
    for (int i = 0; i < CLEN; ++i) {
        float dlt = dp[(size_t)i * 256];
        float u   = up[(size_t)i * 256];
        float du  = dlt * u;
        float y   = u * Dd;
#pragma unroll
        for (int n = 0; n < 8; ++n) {
            float dA = __expf(dlt * a[n]);
            h[n] = dA * h[n] + du * Bsh[n][i];
            y += h[n] * Csh[n][i];
        }
        int l = l0 + i;
        size_t oidx = (b < 2) ? ((size_t)b * 4096 + l) * 1024 + d
                              : ((size_t)(b - 2) * 4096 + (4095 - l)) * 1024 + 512 + d;
        yb[oidx] = (_Float16)y;
    }
}

// ============================================================================
extern "C" void kernel_launch(void* const* d_in, const int* in_sizes, int n_in,
                              void* d_out, int out_size, void* d_ws, size_t ws_size,
                              hipStream_t stream)
{
    const float* hs    = (const float*)d_in[0];   // (2,4096,512)
    const float* w_in  = (const float*)d_in[1];   // (1024,512)
    const float* w_xp  = (const float*)d_in[2];   // (48,256)
    const float* w_dt  = (const float*)d_in[3];   // (256,32)
    const float* b_dt  = (const float*)d_in[4];   // (256,)
    const float* A_log = (const float*)d_in[5];   // (256,8)
    const float* Dpar  = (const float*)d_in[6];   // (256,)
    const float* w_cx  = (const float*)d_in[7];   // (256,1,4)
    const float* w_cz  = (const float*)d_in[8];   // (256,1,4)
    const float* w_out = (const float*)d_in[9];   // (512,1024)
    float* out = (float*)d_out;                   // (2,4096,512)

    float* ws = (float*)d_ws;
    const size_t NX = (size_t)4 * 4096 * 256;       // 4,194,304 floats
    float* x_t  = ws;                               // [4][4096][256] fp32 (dead after conv_x)
    float* z_t  = ws + NX;                          // [4][4096][256] fp32
    float* u_t  = ws + 2 * NX;                      // [4][4096][256] fp32
    float* dlt  = ws + 3 * NX;                      // [4][4096][256] fp32
    float* xdbl = ws + 4 * NX;                      // [4][4096][48]
    float* chS  = xdbl + 786432;                    // [4][256][256]
    float* chB  = chS + 262144;                     // [4][256][8][256]
    float* hin  = chB + 2097152;                    // [4][256][8][256]
    _Float16* hsf = (_Float16*)(hin + 2097152);     // [8192][512] fp16
    _Float16* wif = hsf + 4194304;                  // [1024][512] fp16
    _Float16* wof = wif + 524288;                   // [512][1024] fp16
    // alias (stream order makes this safe): ybuf fp16 over dead x_t (exact fit)
    _Float16* ybf = (_Float16*)x_t;                 // [2][4096][1024] fp16

    k_cast_all     <<<5120,         256, 0, stream>>>(hs, hsf, w_in, wif, w_out, wof);
    k_in_proj_mfma <<<dim3(16, 64), 256, 0, stream>>>(hsf, wif, x_t, z_t);
    k_conv_x4      <<<4096,         256, 0, stream>>>(x_t, w_cx, u_t);
    k_conv_z4      <<<4096,         256, 0, stream>>>(z_t, w_cz, ybf);
    k_xproj        <<<512,          256, 0, stream>>>(u_t, w_xp, xdbl);
    k_dtproj       <<<512,          256, 0, stream>>>(xdbl, w_dt, b_dt, dlt);
    k_scan1        <<<1024,         256, 0, stream>>>(dlt, u_t, xdbl, A_log, chS, chB);
    k_scan2        <<<32,           256, 0, stream>>>(chS, chB, A_log, hin);
    k_scan3        <<<1024,         256, 0, stream>>>(dlt, u_t, xdbl, A_log, Dpar, hin, ybf);
    k_out_proj_mfma<<<dim3(8, 64),  256, 0, stream>>>(ybf, wof, out);
}

// Round 8
// 239.580 us; speedup vs baseline: 1.9707x; 1.0281x over previous
//
#include <hip/hip_runtime.h>
#include <math.h>

// Problem constants
#define LSEQ   4096
#define DHALF  256
#define NSTATE 8
#define NCHUNK 256           // scan chunks
#define CLEN   16            // chunk length (NCHUNK*CLEN = 4096)

typedef __attribute__((ext_vector_type(8))) _Float16 half8;   // MFMA f16 A/B frag
typedef __attribute__((ext_vector_type(4))) _Float16 half4v;
typedef __attribute__((ext_vector_type(4))) float f32x4;

__device__ __forceinline__ float silu_f(float v)     { return v / (1.0f + __expf(-v)); }
__device__ __forceinline__ float softplus_f(float v) { return v > 20.0f ? v : log1pf(__expf(v)); }

// async global->LDS, 16B per lane; LDS dest = wave-uniform base + lane*16
__device__ __forceinline__ void gload16(const void* g, void* l) {
    __builtin_amdgcn_global_load_lds((const __attribute__((address_space(1))) void*)g,
                                     (__attribute__((address_space(3))) void*)l, 16, 0, 0);
}

// ============================================================================
// fp32 -> fp16 cast, all 3 tensors in one launch.
// seg0: hs (n4=1048576), seg1: w_in (131072), seg2: w_out (131072)
// ============================================================================
__global__ __launch_bounds__(256)
void k_cast_all(const float* __restrict__ s0, _Float16* __restrict__ d0,
                const float* __restrict__ s1, _Float16* __restrict__ d1,
                const float* __restrict__ s2, _Float16* __restrict__ d2)
{
    int i = blockIdx.x * 256 + threadIdx.x;
    const float* src; _Float16* dst; int off;
    if (i < 1048576)      { src = s0; dst = d0; off = i; }
    else if (i < 1179648) { src = s1; dst = d1; off = i - 1048576; }
    else                  { src = s2; dst = d2; off = i - 1179648; }
    float4 v = ((const float4*)src)[off];
    half4v h;
    h.x = (_Float16)v.x; h.y = (_Float16)v.y; h.z = (_Float16)v.z; h.w = (_Float16)v.w;
    ((half4v*)dst)[off] = h;
}

// ============================================================================
// MFMA bt-GEMM core (C = A * B^T), fp16 single-product (fp32 accumulate).
// 128(M) x 64(N) tile / block, 4 waves each 64x32 via 4x2 16x16x32 MFMAs.
// BK=64. LDS rows 128B; 16B chunks XOR-swizzled by (row&7) so fragment
// ds_read_b128 is 2-way bank-aliased (free). Swizzle applied on the per-lane
// GLOBAL source chunk (LDS dst stays uniform base + lane*16).
// M0_/N0_ are passed in so callers can XCD-swizzle the block id:
// same-M0 blocks share bid%8 -> same XCD -> A-slab fetched once per XCD.
// (r5-proven core; only the block-coord source changed.)
// ============================================================================
#define GEMM_CORE_F16(K_, M0_, N0_)                                                     \
    const int t = threadIdx.x;                                                          \
    const int wv = t >> 6, lane = t & 63;                                               \
    const int wm = (wv & 1) * 64, wn = (wv >> 1) * 32;                                  \
    const int lm = lane & 15, q = lane >> 4;                                            \
    const int M0 = (M0_), N0 = (N0_);                                                   \
    const int lr = lane >> 3;                  /* row within 8-row group */             \
    const int cc = (lane & 7) ^ lr;            /* swizzled source chunk  */             \
    const size_t gA = (size_t)(M0 + wv * 32 + lr) * K_ + cc * 8;                        \
    const size_t gB = (size_t)(N0 + wv * 16 + lr) * K_ + cc * 8;                        \
    f32x4 acc[4][2] = {};                                                               \
    for (int kb = 0; kb < K_; kb += 64) {                                               \
        __syncthreads();                                                                \
        gload16(Af + gA + kb,               &sA[(wv * 32 +  0) * 64]);                  \
        gload16(Af + gA + (size_t)8  * K_ + kb, &sA[(wv * 32 +  8) * 64]);              \
        gload16(Af + gA + (size_t)16 * K_ + kb, &sA[(wv * 32 + 16) * 64]);              \
        gload16(Af + gA + (size_t)24 * K_ + kb, &sA[(wv * 32 + 24) * 64]);              \
        gload16(Bf + gB + kb,               &sB[(wv * 16 +  0) * 64]);                  \
        gload16(Bf + gB + (size_t)8  * K_ + kb, &sB[(wv * 16 +  8) * 64]);              \
        __syncthreads();                                                                \
        _Pragma("unroll")                                                               \
        for (int kk = 0; kk < 2; ++kk) {                                                \
            const int cpos = (((kk << 2) + q) ^ (lm & 7)) * 8;                          \
            half8 a[4], b[2];                                                           \
            _Pragma("unroll")                                                           \
            for (int i = 0; i < 4; ++i)                                                 \
                a[i] = *(const half8*)&sA[(wm + i * 16 + lm) * 64 + cpos];              \
            _Pragma("unroll")                                                           \
            for (int j = 0; j < 2; ++j)                                                 \
                b[j] = *(const half8*)&sB[(wn + j * 16 + lm) * 64 + cpos];              \
            _Pragma("unroll")                                                           \
            for (int i = 0; i < 4; ++i)                                                 \
                _Pragma("unroll")                                                       \
                for (int j = 0; j < 2; ++j)                                             \
                    acc[i][j] = __builtin_amdgcn_mfma_f32_16x16x32_f16(a[i], b[j], acc[i][j], 0, 0, 0); \
        }                                                                               \
    }

// in_proj: M=8192 (b,l), N=1024 (e), K=512. Epilogue scatter folds direction
// split + reverse. 1D grid 1024; by=bid&63 (M), bx=bid>>6 (N): same-A blocks
// share bid%8 (XCD).
__global__ __launch_bounds__(256)
void k_in_proj_mfma(const _Float16* __restrict__ Af, const _Float16* __restrict__ Bf,
                    float* __restrict__ x_t, float* __restrict__ z_t)
{
    __shared__ _Float16 sA[128 * 64], sB[64 * 64];
    GEMM_CORE_F16(512, (int)(blockIdx.x & 63) * 128, (int)(blockIdx.x >> 6) * 64)
    const int region = N0 >> 8;               // 0..3 uniform per block
    const int eobase = (N0 & 255) + wn;
    float* base = ((region & 1) == 0) ? x_t : z_t;
#pragma unroll
    for (int i = 0; i < 4; ++i) {
#pragma unroll
        for (int r = 0; r < 4; ++r) {
            int m = M0 + wm + i * 16 + q * 4 + r;
            int b = m >> 12, l = m & 4095;
            size_t rowoff = (region < 2)
                ? ((size_t)b * 4096 + l) * 256
                : ((size_t)(b + 2) * 4096 + (4095 - l)) * 256;
#pragma unroll
            for (int j = 0; j < 2; ++j)
                base[rowoff + eobase + j * 16 + lm] = acc[i][j][r];
        }
    }
}

// out_proj: M=8192 (b,l), N=512 (o), K=1024. 1D grid 512; by=bid&63, bx=bid>>6.
__global__ __launch_bounds__(256)
void k_out_proj_mfma(const _Float16* __restrict__ Af, const _Float16* __restrict__ Bf,
                     float* __restrict__ out)
{
    __shared__ _Float16 sA[128 * 64], sB[64 * 64];
    GEMM_CORE_F16(1024, (int)(blockIdx.x & 63) * 128, (int)(blockIdx.x >> 6) * 64)
#pragma unroll
    for (int i = 0; i < 4; ++i) {
#pragma unroll
        for (int r = 0; r < 4; ++r) {
            size_t m = (size_t)(M0 + wm + i * 16 + q * 4 + r);
#pragma unroll
            for (int j = 0; j < 2; ++j)
                out[m * 512 + N0 + wn + j * 16 + lm] = acc[i][j][r];
        }
    }
}

// ============================================================================
// conv_x: dilated (8) causal depthwise conv + SiLU, fp32 float4 (scan path).
// ============================================================================
__global__ __launch_bounds__(256)
void k_conv_x4(const float* __restrict__ x_t, const float* __restrict__ w,
               float* __restrict__ u_t)
{
    int idx = blockIdx.x * 256 + threadIdx.x;
    int b = idx >> 18, rem = idx & 262143;
    int l = rem >> 6, d0 = (rem & 63) * 4;
    const float* base = x_t + (size_t)b * 4096 * 256 + d0;
    float4 wv0 = *(const float4*)(w + (d0 + 0) * 4);
    float4 wv1 = *(const float4*)(w + (d0 + 1) * 4);
    float4 wv2 = *(const float4*)(w + (d0 + 2) * 4);
    float4 wv3 = *(const float4*)(w + (d0 + 3) * 4);
    float4 tp = *(const float4*)(base + (size_t)l * 256);
    float4 a = make_float4(wv0.w * tp.x, wv1.w * tp.y, wv2.w * tp.z, wv3.w * tp.w);
    if (l >= 8) {
        tp = *(const float4*)(base + (size_t)(l - 8) * 256);
        a.x += wv0.z * tp.x; a.y += wv1.z * tp.y; a.z += wv2.z * tp.z; a.w += wv3.z * tp.w;
    }
    if (l >= 16) {
        tp = *(const float4*)(base + (size_t)(l - 16) * 256);
        a.x += wv0.y * tp.x; a.y += wv1.y * tp.y; a.z += wv2.y * tp.z; a.w += wv3.y * tp.w;
    }
    if (l >= 24) {
        tp = *(const float4*)(base + (size_t)(l - 24) * 256);
        a.x += wv0.x * tp.x; a.y += wv1.x * tp.y; a.z += wv2.x * tp.z; a.w += wv3.x * tp.w;
    }
    float4 o = make_float4(silu_f(a.x), silu_f(a.y), silu_f(a.z), silu_f(a.w));
    *(float4*)(u_t + ((size_t)b * 4096 + l) * 256 + d0) = o;
}

// ============================================================================
// conv_z: dilation-1 causal conv + SiLU -> ybuf z-channels (fp16),
// direction un-reversal folded in. ybuf: [2][4096][1024] fp16
// ============================================================================
__global__ __launch_bounds__(256)
void k_conv_z4(const float* __restrict__ z_t, const float* __restrict__ w,
               _Float16* __restrict__ yb)
{
    int idx = blockIdx.x * 256 + threadIdx.x;
    int b = idx >> 18, rem = idx & 262143;
    int l = rem >> 6, d0 = (rem & 63) * 4;
    const float* base = z_t + (size_t)b * 4096 * 256 + d0;
    float4 wv0 = *(const float4*)(w + (d0 + 0) * 4);
    float4 wv1 = *(const float4*)(w + (d0 + 1) * 4);
    float4 wv2 = *(const float4*)(w + (d0 + 2) * 4);
    float4 wv3 = *(const float4*)(w + (d0 + 3) * 4);
    float4 tp = *(const float4*)(base + (size_t)l * 256);
    float4 a = make_float4(wv0.w * tp.x, wv1.w * tp.y, wv2.w * tp.z, wv3.w * tp.w);
    if (l >= 1) {
        tp = *(const float4*)(base + (size_t)(l - 1) * 256);
        a.x += wv0.z * tp.x; a.y += wv1.z * tp.y; a.z += wv2.z * tp.z; a.w += wv3.z * tp.w;
    }
    if (l >= 2) {
        tp = *(const float4*)(base + (size_t)(l - 2) * 256);
        a.x += wv0.y * tp.x; a.y += wv1.y * tp.y; a.z += wv2.y * tp.z; a.w += wv3.y * tp.w;
    }
    if (l >= 3) {
        tp = *(const float4*)(base + (size_t)(l - 3) * 256);
        a.x += wv0.x * tp.x; a.y += wv1.x * tp.y; a.z += wv2.x * tp.z; a.w += wv3.x * tp.w;
    }
    size_t oidx = (b < 2) ? ((size_t)b * 4096 + l) * 1024 + 256 + d0
                          : ((size_t)(b - 2) * 4096 + (4095 - l)) * 1024 + 768 + d0;
    half4v h;
    h.x = (_Float16)silu_f(a.x); h.y = (_Float16)silu_f(a.y);
    h.z = (_Float16)silu_f(a.z); h.w = (_Float16)silu_f(a.w);
    *(half4v*)(yb + oidx) = h;
}

// ============================================================================
// x_proj: xdbl[m][e] = sum_d u_t[m][d] * Wx[e][d];  M=16384, N=48, K=256
// 512 blocks of 32 rows.
// ============================================================================
__global__ __launch_bounds__(256)
void k_xproj(const float* __restrict__ U, const float* __restrict__ W,
             float* __restrict__ xdbl)
{
    __shared__ float Xs[32][260];
    __shared__ float Ws[48][68];
    const int t  = threadIdx.x;
    const int m0 = blockIdx.x * 32;
#pragma unroll
    for (int it = 0; it < 8; ++it) {       // 32x256 = 2048 float4
        int idx = t + 256 * it;
        int row = idx >> 6, c = (idx & 63) * 4;
        *(float4*)&Xs[row][c] = *(const float4*)(U + (size_t)(m0 + row) * 256 + c);
    }
    const int r  = t >> 3;                 // 0..31
    const int j0 = (t & 7) * 6;            // 0..42
    float acc[6] = {};
    for (int kb = 0; kb < 256; kb += 64) {
        __syncthreads();
#pragma unroll
        for (int it = 0; it < 3; ++it) {   // 48x64 = 768 float4
            int idx = t + 256 * it;
            int wr = idx >> 4, wc = (idx & 15) * 4;
            *(float4*)&Ws[wr][wc] = *(const float4*)(W + (size_t)wr * 256 + kb + wc);
        }
        __syncthreads();
#pragma unroll
        for (int k4 = 0; k4 < 16; ++k4) {
            float4 x = *(const float4*)&Xs[r][kb + k4 * 4];
#pragma unroll
            for (int jj = 0; jj < 6; ++jj) {
                float4 wv = *(const float4*)&Ws[j0 + jj][k4 * 4];
                acc[jj] = fmaf(x.x, wv.x, acc[jj]);
                acc[jj] = fmaf(x.y, wv.y, acc[jj]);
                acc[jj] = fmaf(x.z, wv.z, acc[jj]);
                acc[jj] = fmaf(x.w, wv.w, acc[jj]);
            }
        }
    }
    float* dst = xdbl + (size_t)(m0 + r) * 48 + j0;
#pragma unroll
    for (int jj = 0; jj < 6; ++jj) dst[jj] = acc[jj];
}

// ============================================================================
// dt_proj + softplus (broadcast structure); delta fp32 (scan input).
// ============================================================================
__global__ __launch_bounds__(256)
void k_dtproj(const float* __restrict__ xdbl, const float* __restrict__ Wdt,
              const float* __restrict__ bdt, float* __restrict__ delta_t)
{
    __shared__ float Xs[32][32];
    const int t  = threadIdx.x;            // d = t
    const int m0 = blockIdx.x * 32;
    {
        int r = t >> 3;
        int c = (t & 7) * 4;
        *(float4*)&Xs[r][c] = *(const float4*)(xdbl + (size_t)(m0 + r) * 48 + c);
    }
    float w[32];
    {
        const float4* wp = (const float4*)(Wdt + t * 32);
#pragma unroll
        for (int j = 0; j < 8; ++j) {
            float4 v = wp[j];
            w[4*j+0] = v.x; w[4*j+1] = v.y; w[4*j+2] = v.z; w[4*j+3] = v.w;
        }
    }
    const float bias = bdt[t];
    __syncthreads();
    for (int m = 0; m < 32; ++m) {
        const float4* xr = (const float4*)&Xs[m][0];
        float acc = bias;
#pragma unroll
        for (int j = 0; j < 8; ++j) {
            float4 xv = xr[j];
            acc = fmaf(xv.x, w[4*j+0], acc);
            acc = fmaf(xv.y, w[4*j+1], acc);
            acc = fmaf(xv.z, w[4*j+2], acc);
            acc = fmaf(xv.w, w[4*j+3], acc);
        }
        delta_t[(size_t)(m0 + m) * 256 + t] = softplus_f(acc);
    }
}

// ============================================================================
// Selective scan, chunked (NCHUNK=256 chunks x CLEN=16 steps). All fp32.
// ============================================================================
__global__ __launch_bounds__(256)
void k_scan1(const float* __restrict__ delta_t, const float* __restrict__ u_t,
             const float* __restrict__ xdbl, const float* __restrict__ A_log,
             float* __restrict__ chS, float* __restrict__ chB)
{
    __shared__ float Bsh[8][CLEN];
    const int b = blockIdx.x >> 8;
    const int c = blockIdx.x & 255;
    const int d = threadIdx.x;
    const int l0 = c * CLEN;
    if (threadIdx.x < 128) {
        int i = threadIdx.x >> 3, n = threadIdx.x & 7;
        Bsh[n][i] = xdbl[((size_t)b * 4096 + l0 + i) * 48 + 32 + n];
    }
    float a[8];
#pragma unroll
    for (int n = 0; n < 8; ++n) a[n] = -__expf(A_log[d * 8 + n]);
    float h[8];
#pragma unroll
    for (int n = 0; n < 8; ++n) h[n] = 0.0f;
    float S = 0.0f;
    __syncthreads();
    const float* dp = delta_t + ((size_t)b * 4096 + l0) * 256 + d;
    const float* up = u_t     + ((size_t)b * 4096 + l0) * 256 + d;
    for (int i = 0; i < CLEN; ++i) {
        float dlt = dp[(size_t)i * 256];
        float u   = up[(size_t)i * 256];
        float du  = dlt * u;
        S += dlt;
#pragma unroll
        for (int n = 0; n < 8; ++n) {
            float dA = __expf(dlt * a[n]);
            h[n] = dA * h[n] + du * Bsh[n][i];
        }
    }
    chS[((size_t)b * NCHUNK + c) * 256 + d] = S;
#pragma unroll
    for (int n = 0; n < 8; ++n)
        chB[(((size_t)b * NCHUNK + c) * 8 + n) * 256 + d] = h[n];
}

// per (b,n): chain over 256 chunks, loads batched 16-ahead.
__global__ __launch_bounds__(256)
void k_scan2(const float* __restrict__ chS, const float* __restrict__ chB,
             const float* __restrict__ A_log, float* __restrict__ hinit)
{
    const int b = blockIdx.x >> 3;
    const int n = blockIdx.x & 7;
    const int d = threadIdx.x;
    const float a = -__expf(A_log[d * 8 + n]);
    float h = 0.0f;
    for (int cb = 0; cb < NCHUNK; cb += 16) {
        float S[16], Bc[16];
#pragma unroll
        for (int j = 0; j < 16; ++j) {
            S[j]  = chS[((size_t)b * NCHUNK + cb + j) * 256 + d];
            Bc[j] = chB[(((size_t)b * NCHUNK + cb + j) * 8 + n) * 256 + d];
        }
#pragma unroll
        for (int j = 0; j < 16; ++j) {
            hinit[(((size_t)b * NCHUNK + cb + j) * 8 + n) * 256 + d] = h;
            h = __expf(a * S[j]) * h + Bc[j];
        }
    }
}

__global__ __launch_bounds__(256)
void k_scan3(const float* __restrict__ delta_t, const float* __restrict__ u_t,
             const float* __restrict__ xdbl, const float* __restrict__ A_log,
             const float* __restrict__ Dp, const float* __restrict__ hinit,
             _Float16* __restrict__ yb)
{
    __shared__ float Bsh[8][CLEN];
    __shared__ float Csh[8][CLEN];
    const int b = blockIdx.x >> 8;
    const int c = blockIdx.x & 255;
    const int d = threadIdx.x;
    const int l0 = c * CLEN;
    {
        int s = threadIdx.x;
        if (s < 128) {
            int i = s >> 3, n = s & 7;
            Bsh[n][i] = xdbl[((size_t)b * 4096 + l0 + i) * 48 + 32 + n];
        } else {
            int s2 = s - 128;
            int i = s2 >> 3, n = s2 & 7;
            Csh[n][i] = xdbl[((size_t)b * 4096 + l0 + i) * 48 + 40 + n];
        }
    }
    float a[8], h[8];
#pragma unroll
    for (int n = 0; n < 8; ++n) {
        a[n] = -__expf(A_log[d * 8 + n]);
        h[n] = hinit[(((size_t)b * NCHUNK + c) * 8 + n) * 256 + d];
    }
    const float Dd = Dp[d];
    __syncthreads();
    const float* dp = delta_t + ((size_t)b * 4096 + l0) * 256 + d;
    const float* up = u_t     + ((size_t)b * 4096 + l0) * 256 + d;
    for (int i = 0; i < CLEN; ++i) {
        float dlt = dp[(size_t)i * 256];
        float u   = up[(size_t)i * 256];
        float du  = dlt * u;
        float y   = u * Dd;
#pragma unroll
        for (int n = 0; n < 8; ++n) {
            float dA = __expf(dlt * a[n]);
            h[n] = dA * h[n] + du * Bsh[n][i];
            y += h[n] * Csh[n][i];
        }
        int l = l0 + i;
        size_t oidx = (b < 2) ? ((size_t)b * 4096 + l) * 1024 + d
                              : ((size_t)(b - 2) * 4096 + (4095 - l)) * 1024 + 512 + d;
        yb[oidx] = (_Float16)y;
    }
}

// ============================================================================
extern "C" void kernel_launch(void* const* d_in, const int* in_sizes, int n_in,
                              void* d_out, int out_size, void* d_ws, size_t ws_size,
                              hipStream_t stream)
{
    const float* hs    = (const float*)d_in[0];   // (2,4096,512)
    const float* w_in  = (const float*)d_in[1];   // (1024,512)
    const float* w_xp  = (const float*)d_in[2];   // (48,256)
    const float* w_dt  = (const float*)d_in[3];   // (256,32)
    const float* b_dt  = (const float*)d_in[4];   // (256,)
    const float* A_log = (const float*)d_in[5];   // (256,8)
    const float* Dpar  = (const float*)d_in[6];   // (256,)
    const float* w_cx  = (const float*)d_in[7];   // (256,1,4)
    const float* w_cz  = (const float*)d_in[8];   // (256,1,4)
    const float* w_out = (const float*)d_in[9];   // (512,1024)
    float* out = (float*)d_out;                   // (2,4096,512)

    const size_t NX = (size_t)4 * 4096 * 256;       // 4,194,304 elements
    float* ws   = (float*)d_ws;
    float* x_t  = ws;                               // [4][4096][256] fp32 (dead after conv_x)
    float* z_t  = ws + NX;                          // [4][4096][256] fp32
    float* u_t  = ws + 2 * NX;                      // [4][4096][256] fp32
    float* dlt  = ws + 3 * NX;                      // [4][4096][256] fp32
    float* xdbl = ws + 4 * NX;                      // [4][4096][48]
    float* chS  = xdbl + 786432;                    // [4][256][256]
    float* chB  = chS + 262144;                     // [4][256][8][256]
    float* hin  = chB + 2097152;                    // [4][256][8][256]
    _Float16* hsf = (_Float16*)(hin + 2097152);     // [8192][512] fp16
    _Float16* wif = hsf + 4194304;                  // [1024][512] fp16
    _Float16* wof = wif + 524288;                   // [512][1024] fp16
    // alias (stream order makes this safe): ybuf fp16 over dead x_t (exact fit)
    _Float16* ybf = (_Float16*)x_t;                 // [2][4096][1024] fp16

    k_cast_all     <<<5120,  256, 0, stream>>>(hs, hsf, w_in, wif, w_out, wof);
    k_in_proj_mfma <<<1024,  256, 0, stream>>>(hsf, wif, x_t, z_t);
    k_conv_x4      <<<4096,  256, 0, stream>>>(x_t, w_cx, u_t);
    k_conv_z4      <<<4096,  256, 0, stream>>>(z_t, w_cz, ybf);
    k_xproj        <<<512,   256, 0, stream>>>(u_t, w_xp, xdbl);
    k_dtproj       <<<512,   256, 0, stream>>>(xdbl, w_dt, b_dt, dlt);
    k_scan1        <<<1024,  256, 0, stream>>>(dlt, u_t, xdbl, A_log, chS, chB);
    k_scan2        <<<32,    256, 0, stream>>>(chS, chB, A_log, hin);
    k_scan3        <<<1024,  256, 0, stream>>>(dlt, u_t, xdbl, A_log, Dpar, hin, ybf);
    k_out_proj_mfma<<<512,   256, 0, stream>>>(ybf, wof, out);
}

// Round 9
// 235.062 us; speedup vs baseline: 2.0086x; 1.0192x over previous
//
#include <hip/hip_runtime.h>
#include <math.h>

// Problem constants
#define LSEQ   4096
#define DHALF  256
#define NSTATE 8
#define NCHUNK 256           // scan chunks
#define CLEN   16            // chunk length (NCHUNK*CLEN = 4096)

typedef __attribute__((ext_vector_type(8))) _Float16 half8;   // MFMA f16 A/B frag
typedef __attribute__((ext_vector_type(4))) _Float16 half4v;
typedef __attribute__((ext_vector_type(4))) float f32x4;

__device__ __forceinline__ float silu_f(float v)     { return v / (1.0f + __expf(-v)); }
__device__ __forceinline__ float softplus_f(float v) { return v > 20.0f ? v : log1pf(__expf(v)); }

// async global->LDS, 16B per lane; LDS dest = wave-uniform base + lane*16
__device__ __forceinline__ void gload16(const void* g, void* l) {
    __builtin_amdgcn_global_load_lds((const __attribute__((address_space(1))) void*)g,
                                     (__attribute__((address_space(3))) void*)l, 16, 0, 0);
}

// ============================================================================
// fp32 -> fp16 cast (3 tensors) + Wdt transpose, one launch.
// seg0: hs (n4=1048576), seg1: w_in (131072), seg2: w_out (131072),
// seg3: Wdt[256][32] -> WT[32][256] (scalar, 8192 elems)
// ============================================================================
__global__ __launch_bounds__(256)
void k_cast_all(const float* __restrict__ s0, _Float16* __restrict__ d0,
                const float* __restrict__ s1, _Float16* __restrict__ d1,
                const float* __restrict__ s2, _Float16* __restrict__ d2,
                const float* __restrict__ wdt, float* __restrict__ wtT)
{
    int i = blockIdx.x * 256 + threadIdx.x;
    if (i >= 1310720) {                       // seg3: transpose Wdt
        int j = i - 1310720;                  // 0..8191
        int d = j >> 5, k = j & 31;
        wtT[k * 256 + d] = wdt[j];
        return;
    }
    const float* src; _Float16* dst; int off;
    if (i < 1048576)      { src = s0; dst = d0; off = i; }
    else if (i < 1179648) { src = s1; dst = d1; off = i - 1048576; }
    else                  { src = s2; dst = d2; off = i - 1179648; }
    float4 v = ((const float4*)src)[off];
    half4v h;
    h.x = (_Float16)v.x; h.y = (_Float16)v.y; h.z = (_Float16)v.z; h.w = (_Float16)v.w;
    ((half4v*)dst)[off] = h;
}

// ============================================================================
// MFMA bt-GEMM core (C = A * B^T), fp16 single-product (fp32 accumulate).
// 128(M) x 64(N) tile / block, 4 waves each 64x32 via 4x2 16x16x32 MFMAs.
// BK=64. LDS rows 128B; 16B chunks XOR-swizzled by (row&7) so fragment
// ds_read_b128 is 2-way bank-aliased (free). Swizzle applied on the per-lane
// GLOBAL source chunk (LDS dst stays uniform base + lane*16).
// M0_/N0_ passed in for XCD-swizzled block ids: same-M0 blocks share bid%8
// -> same XCD -> A-slab fetched ~once per XCD.
// ============================================================================
#define GEMM_CORE_F16(K_, M0_, N0_)                                                     \
    const int t = threadIdx.x;                                                          \
    const int wv = t >> 6, lane = t & 63;                                               \
    const int wm = (wv & 1) * 64, wn = (wv >> 1) * 32;                                  \
    const int lm = lane & 15, q = lane >> 4;                                            \
    const int M0 = (M0_), N0 = (N0_);                                                   \
    const int lr = lane >> 3;                  /* row within 8-row group */             \
    const int cc = (lane & 7) ^ lr;            /* swizzled source chunk  */             \
    const size_t gA = (size_t)(M0 + wv * 32 + lr) * K_ + cc * 8;                        \
    const size_t gB = (size_t)(N0 + wv * 16 + lr) * K_ + cc * 8;                        \
    f32x4 acc[4][2] = {};                                                               \
    for (int kb = 0; kb < K_; kb += 64) {                                               \
        __syncthreads();                                                                \
        gload16(Af + gA + kb,               &sA[(wv * 32 +  0) * 64]);                  \
        gload16(Af + gA + (size_t)8  * K_ + kb, &sA[(wv * 32 +  8) * 64]);              \
        gload16(Af + gA + (size_t)16 * K_ + kb, &sA[(wv * 32 + 16) * 64]);              \
        gload16(Af + gA + (size_t)24 * K_ + kb, &sA[(wv * 32 + 24) * 64]);              \
        gload16(Bf + gB + kb,               &sB[(wv * 16 +  0) * 64]);                  \
        gload16(Bf + gB + (size_t)8  * K_ + kb, &sB[(wv * 16 +  8) * 64]);              \
        __syncthreads();                                                                \
        _Pragma("unroll")                                                               \
        for (int kk = 0; kk < 2; ++kk) {                                                \
            const int cpos = (((kk << 2) + q) ^ (lm & 7)) * 8;                          \
            half8 a[4], b[2];                                                           \
            _Pragma("unroll")                                                           \
            for (int i = 0; i < 4; ++i)                                                 \
                a[i] = *(const half8*)&sA[(wm + i * 16 + lm) * 64 + cpos];              \
            _Pragma("unroll")                                                           \
            for (int j = 0; j < 2; ++j)                                                 \
                b[j] = *(const half8*)&sB[(wn + j * 16 + lm) * 64 + cpos];              \
            _Pragma("unroll")                                                           \
            for (int i = 0; i < 4; ++i)                                                 \
                _Pragma("unroll")                                                       \
                for (int j = 0; j < 2; ++j)                                             \
                    acc[i][j] = __builtin_amdgcn_mfma_f32_16x16x32_f16(a[i], b[j], acc[i][j], 0, 0, 0); \
        }                                                                               \
    }

// in_proj: M=8192 (b,l), N=1024 (e), K=512. Epilogue scatter folds direction
// split + reverse. 1D grid 1024; by=bid&63 (M), bx=bid>>6 (N).
__global__ __launch_bounds__(256)
void k_in_proj_mfma(const _Float16* __restrict__ Af, const _Float16* __restrict__ Bf,
                    float* __restrict__ x_t, float* __restrict__ z_t)
{
    __shared__ _Float16 sA[128 * 64], sB[64 * 64];
    GEMM_CORE_F16(512, (int)(blockIdx.x & 63) * 128, (int)(blockIdx.x >> 6) * 64)
    const int region = N0 >> 8;               // 0..3 uniform per block
    const int eobase = (N0 & 255) + wn;
    float* base = ((region & 1) == 0) ? x_t : z_t;
#pragma unroll
    for (int i = 0; i < 4; ++i) {
#pragma unroll
        for (int r = 0; r < 4; ++r) {
            int m = M0 + wm + i * 16 + q * 4 + r;
            int b = m >> 12, l = m & 4095;
            size_t rowoff = (region < 2)
                ? ((size_t)b * 4096 + l) * 256
                : ((size_t)(b + 2) * 4096 + (4095 - l)) * 256;
#pragma unroll
            for (int j = 0; j < 2; ++j)
                base[rowoff + eobase + j * 16 + lm] = acc[i][j][r];
        }
    }
}

// out_proj: M=8192 (b,l), N=512 (o), K=1024. 1D grid 512; by=bid&63, bx=bid>>6.
__global__ __launch_bounds__(256)
void k_out_proj_mfma(const _Float16* __restrict__ Af, const _Float16* __restrict__ Bf,
                     float* __restrict__ out)
{
    __shared__ _Float16 sA[128 * 64], sB[64 * 64];
    GEMM_CORE_F16(1024, (int)(blockIdx.x & 63) * 128, (int)(blockIdx.x >> 6) * 64)
#pragma unroll
    for (int i = 0; i < 4; ++i) {
#pragma unroll
        for (int r = 0; r < 4; ++r) {
            size_t m = (size_t)(M0 + wm + i * 16 + q * 4 + r);
#pragma unroll
            for (int j = 0; j < 2; ++j)
                out[m * 512 + N0 + wn + j * 16 + lm] = acc[i][j][r];
        }
    }
}

// ============================================================================
// conv_x: dilated (8) causal depthwise conv + SiLU, fp32 float4 (scan path).
// ============================================================================
__global__ __launch_bounds__(256)
void k_conv_x4(const float* __restrict__ x_t, const float* __restrict__ w,
               float* __restrict__ u_t)
{
    int idx = blockIdx.x * 256 + threadIdx.x;
    int b = idx >> 18, rem = idx & 262143;
    int l = rem >> 6, d0 = (rem & 63) * 4;
    const float* base = x_t + (size_t)b * 4096 * 256 + d0;
    float4 wv0 = *(const float4*)(w + (d0 + 0) * 4);
    float4 wv1 = *(const float4*)(w + (d0 + 1) * 4);
    float4 wv2 = *(const float4*)(w + (d0 + 2) * 4);
    float4 wv3 = *(const float4*)(w + (d0 + 3) * 4);
    float4 tp = *(const float4*)(base + (size_t)l * 256);
    float4 a = make_float4(wv0.w * tp.x, wv1.w * tp.y, wv2.w * tp.z, wv3.w * tp.w);
    if (l >= 8) {
        tp = *(const float4*)(base + (size_t)(l - 8) * 256);
        a.x += wv0.z * tp.x; a.y += wv1.z * tp.y; a.z += wv2.z * tp.z; a.w += wv3.z * tp.w;
    }
    if (l >= 16) {
        tp = *(const float4*)(base + (size_t)(l - 16) * 256);
        a.x += wv0.y * tp.x; a.y += wv1.y * tp.y; a.z += wv2.y * tp.z; a.w += wv3.y * tp.w;
    }
    if (l >= 24) {
        tp = *(const float4*)(base + (size_t)(l - 24) * 256);
        a.x += wv0.x * tp.x; a.y += wv1.x * tp.y; a.z += wv2.x * tp.z; a.w += wv3.x * tp.w;
    }
    float4 o = make_float4(silu_f(a.x), silu_f(a.y), silu_f(a.z), silu_f(a.w));
    *(float4*)(u_t + ((size_t)b * 4096 + l) * 256 + d0) = o;
}

// ============================================================================
// conv_z: dilation-1 causal conv + SiLU -> ybuf z-channels (fp16),
// direction un-reversal folded in. ybuf: [2][4096][1024] fp16
// ============================================================================
__global__ __launch_bounds__(256)
void k_conv_z4(const float* __restrict__ z_t, const float* __restrict__ w,
               _Float16* __restrict__ yb)
{
    int idx = blockIdx.x * 256 + threadIdx.x;
    int b = idx >> 18, rem = idx & 262143;
    int l = rem >> 6, d0 = (rem & 63) * 4;
    const float* base = z_t + (size_t)b * 4096 * 256 + d0;
    float4 wv0 = *(const float4*)(w + (d0 + 0) * 4);
    float4 wv1 = *(const float4*)(w + (d0 + 1) * 4);
    float4 wv2 = *(const float4*)(w + (d0 + 2) * 4);
    float4 wv3 = *(const float4*)(w + (d0 + 3) * 4);
    float4 tp = *(const float4*)(base + (size_t)l * 256);
    float4 a = make_float4(wv0.w * tp.x, wv1.w * tp.y, wv2.w * tp.z, wv3.w * tp.w);
    if (l >= 1) {
        tp = *(const float4*)(base + (size_t)(l - 1) * 256);
        a.x += wv0.z * tp.x; a.y += wv1.z * tp.y; a.z += wv2.z * tp.z; a.w += wv3.z * tp.w;
    }
    if (l >= 2) {
        tp = *(const float4*)(base + (size_t)(l - 2) * 256);
        a.x += wv0.y * tp.x; a.y += wv1.y * tp.y; a.z += wv2.y * tp.z; a.w += wv3.y * tp.w;
    }
    if (l >= 3) {
        tp = *(const float4*)(base + (size_t)(l - 3) * 256);
        a.x += wv0.x * tp.x; a.y += wv1.x * tp.y; a.z += wv2.x * tp.z; a.w += wv3.x * tp.w;
    }
    size_t oidx = (b < 2) ? ((size_t)b * 4096 + l) * 1024 + 256 + d0
                          : ((size_t)(b - 2) * 4096 + (4095 - l)) * 1024 + 768 + d0;
    half4v h;
    h.x = (_Float16)silu_f(a.x); h.y = (_Float16)silu_f(a.y);
    h.z = (_Float16)silu_f(a.z); h.w = (_Float16)silu_f(a.w);
    *(half4v*)(yb + oidx) = h;
}

// ============================================================================
// x_proj: xdbl[m][e] = sum_d u_t[m][d] * Wx[e][d];  M=16384, N=48, K=256
// 512 blocks of 32 rows.
// ============================================================================
__global__ __launch_bounds__(256)
void k_xproj(const float* __restrict__ U, const float* __restrict__ W,
             float* __restrict__ xdbl)
{
    __shared__ float Xs[32][260];
    __shared__ float Ws[48][68];
    const int t  = threadIdx.x;
    const int m0 = blockIdx.x * 32;
#pragma unroll
    for (int it = 0; it < 8; ++it) {       // 32x256 = 2048 float4
        int idx = t + 256 * it;
        int row = idx >> 6, c = (idx & 63) * 4;
        *(float4*)&Xs[row][c] = *(const float4*)(U + (size_t)(m0 + row) * 256 + c);
    }
    const int r  = t >> 3;                 // 0..31
    const int j0 = (t & 7) * 6;            // 0..42
    float acc[6] = {};
    for (int kb = 0; kb < 256; kb += 64) {
        __syncthreads();
#pragma unroll
        for (int it = 0; it < 3; ++it) {   // 48x64 = 768 float4
            int idx = t + 256 * it;
            int wr = idx >> 4, wc = (idx & 15) * 4;
            *(float4*)&Ws[wr][wc] = *(const float4*)(W + (size_t)wr * 256 + kb + wc);
        }
        __syncthreads();
#pragma unroll
        for (int k4 = 0; k4 < 16; ++k4) {
            float4 x = *(const float4*)&Xs[r][kb + k4 * 4];
#pragma unroll
            for (int jj = 0; jj < 6; ++jj) {
                float4 wv = *(const float4*)&Ws[j0 + jj][k4 * 4];
                acc[jj] = fmaf(x.x, wv.x, acc[jj]);
                acc[jj] = fmaf(x.y, wv.y, acc[jj]);
                acc[jj] = fmaf(x.z, wv.z, acc[jj]);
                acc[jj] = fmaf(x.w, wv.w, acc[jj]);
            }
        }
    }
    float* dst = xdbl + (size_t)(m0 + r) * 48 + j0;
#pragma unroll
    for (int jj = 0; jj < 6; ++jj) dst[jj] = acc[jj];
}

// ============================================================================
// dt_proj + softplus. Thread = channel d; W read from TRANSPOSED WT[32][256]
// so w[k]=WT[k*256+d] is a coalesced wave-load (the old per-thread row load
// scattered 64 lanes over 64 cache lines -> latency-bound, 55-75us in r8).
// 1024 blocks x 16 m-rows = 4 blocks/CU.
// ============================================================================
__global__ __launch_bounds__(256)
void k_dtproj(const float* __restrict__ xdbl, const float* __restrict__ WT,
              const float* __restrict__ bdt, float* __restrict__ delta_t)
{
    __shared__ float Xs[16][32];
    const int t  = threadIdx.x;            // d = t
    const int m0 = blockIdx.x * 16;
    if (t < 128) {                         // 16x32 floats = 128 float4
        int r = t >> 3, c = (t & 7) * 4;
        *(float4*)&Xs[r][c] = *(const float4*)(xdbl + (size_t)(m0 + r) * 48 + c);
    }
    float w[32];
#pragma unroll
    for (int k = 0; k < 32; ++k) w[k] = WT[k * 256 + t];
    const float bias = bdt[t];
    __syncthreads();
#pragma unroll
    for (int m = 0; m < 16; ++m) {
        const float4* xr = (const float4*)&Xs[m][0];
        float acc = bias;
#pragma unroll
        for (int j = 0; j < 8; ++j) {
            float4 xv = xr[j];
            acc = fmaf(xv.x, w[4*j+0], acc);
            acc = fmaf(xv.y, w[4*j+1], acc);
            acc = fmaf(xv.z, w[4*j+2], acc);
            acc = fmaf(xv.w, w[4*j+3], acc);
        }
        delta_t[(size_t)(m0 + m) * 256 + t] = softplus_f(acc);
    }
}

// ============================================================================
// Selective scan, chunked (NCHUNK=256 chunks x CLEN=16 steps). All fp32.
// ============================================================================
__global__ __launch_bounds__(256)
void k_scan1(const float* __restrict__ delta_t, const float* __restrict__ u_t,
             const float* __restrict__ xdbl, const float* __restrict__ A_log,
             float* __restrict__ chS, float* __restrict__ chB)
{
    __shared__ float Bsh[8][CLEN];
    const int b = blockIdx.x >> 8;
    const int c = blockIdx.x & 255;
    const int d = threadIdx.x;
    const int l0 = c * CLEN;
    if (threadIdx.x < 128) {
        int i = threadIdx.x >> 3, n = threadIdx.x & 7;
        Bsh[n][i] = xdbl[((size_t)b * 4096 + l0 + i) * 48 + 32 + n];
    }
    float a[8];
#pragma unroll
    for (int n = 0; n < 8; ++n) a[n] = -__expf(A_log[d * 8 + n]);
    float h[8];
#pragma unroll
    for (int n = 0; n < 8; ++n) h[n] = 0.0f;
    float S = 0.0f;
    __syncthreads();
    const float* dp = delta_t + ((size_t)b * 4096 + l0) * 256 + d;
    const float* up = u_t     + ((size_t)b * 4096 + l0) * 256 + d;
    for (int i = 0; i < CLEN; ++i) {
        float dlt = dp[(size_t)i * 256];
        float u   = up[(size_t)i * 256];
        float du  = dlt * u;
        S += dlt;
#pragma unroll
        for (int n = 0; n < 8; ++n) {
            float dA = __expf(dlt * a[n]);
            h[n] = dA * h[n] + du * Bsh[n][i];
        }
    }
    chS[((size_t)b * NCHUNK + c) * 256 + d] = S;
#pragma unroll
    for (int n = 0; n < 8; ++n)
        chB[(((size_t)b * NCHUNK + c) * 8 + n) * 256 + d] = h[n];
}

// per (b,n): chain over 256 chunks, loads batched 16-ahead.
__global__ __launch_bounds__(256)
void k_scan2(const float* __restrict__ chS, const float* __restrict__ chB,
             const float* __restrict__ A_log, float* __restrict__ hinit)
{
    const int b = blockIdx.x >> 3;
    const int n = blockIdx.x & 7;
    const int d = threadIdx.x;
    const float a = -__expf(A_log[d * 8 + n]);
    float h = 0.0f;
    for (int cb = 0; cb < NCHUNK; cb += 16) {
        float S[16], Bc[16];
#pragma unroll
        for (int j = 0; j < 16; ++j) {
            S[j]  = chS[((size_t)b * NCHUNK + cb + j) * 256 + d];
            Bc[j] = chB[(((size_t)b * NCHUNK + cb + j) * 8 + n) * 256 + d];
        }
#pragma unroll
        for (int j = 0; j < 16; ++j) {
            hinit[(((size_t)b * NCHUNK + cb + j) * 8 + n) * 256 + d] = h;
            h = __expf(a * S[j]) * h + Bc[j];
        }
    }
}

__global__ __launch_bounds__(256)
void k_scan3(const float* __restrict__ delta_t, const float* __restrict__ u_t,
             const float* __restrict__ xdbl, const float* __restrict__ A_log,
             const float* __restrict__ Dp, const float* __restrict__ hinit,
             _Float16* __restrict__ yb)
{
    __shared__ float Bsh[8][CLEN];
    __shared__ float Csh[8][CLEN];
    const int b = blockIdx.x >> 8;
    const int c = blockIdx.x & 255;
    const int d = threadIdx.x;
    const int l0 = c * CLEN;
    {
        int s = threadIdx.x;
        if (s < 128) {
            int i = s >> 3, n = s & 7;
            Bsh[n][i] = xdbl[((size_t)b * 4096 + l0 + i) * 48 + 32 + n];
        } else {
            int s2 = s - 128;
            int i = s2 >> 3, n = s2 & 7;
            Csh[n][i] = xdbl[((size_t)b * 4096 + l0 + i) * 48 + 40 + n];
        }
    }
    float a[8], h[8];
#pragma unroll
    for (int n = 0; n < 8; ++n) {
        a[n] = -__expf(A_log[d * 8 + n]);
        h[n] = hinit[(((size_t)b * NCHUNK + c) * 8 + n) * 256 + d];
    }
    const float Dd = Dp[d];
    __syncthreads();
    const float* dp = delta_t + ((size_t)b * 4096 + l0) * 256 + d;
    const float* up = u_t     + ((size_t)b * 4096 + l0) * 256 + d;
    for (int i = 0; i < CLEN; ++i) {
        float dlt = dp[(size_t)i * 256];
        float u   = up[(size_t)i * 256];
        float du  = dlt * u;
        float y   = u * Dd;
#pragma unroll
        for (int n = 0; n < 8; ++n) {
            float dA = __expf(dlt * a[n]);
            h[n] = dA * h[n] + du * Bsh[n][i];
            y += h[n] * Csh[n][i];
        }
        int l = l0 + i;
        size_t oidx = (b < 2) ? ((size_t)b * 4096 + l) * 1024 + d
                              : ((size_t)(b - 2) * 4096 + (4095 - l)) * 1024 + 512 + d;
        yb[oidx] = (_Float16)y;
    }
}

// ============================================================================
extern "C" void kernel_launch(void* const* d_in, const int* in_sizes, int n_in,
                              void* d_out, int out_size, void* d_ws, size_t ws_size,
                              hipStream_t stream)
{
    const float* hs    = (const float*)d_in[0];   // (2,4096,512)
    const float* w_in  = (const float*)d_in[1];   // (1024,512)
    const float* w_xp  = (const float*)d_in[2];   // (48,256)
    const float* w_dt  = (const float*)d_in[3];   // (256,32)
    const float* b_dt  = (const float*)d_in[4];   // (256,)
    const float* A_log = (const float*)d_in[5];   // (256,8)
    const float* Dpar  = (const float*)d_in[6];   // (256,)
    const float* w_cx  = (const float*)d_in[7];   // (256,1,4)
    const float* w_cz  = (const float*)d_in[8];   // (256,1,4)
    const float* w_out = (const float*)d_in[9];   // (512,1024)
    float* out = (float*)d_out;                   // (2,4096,512)

    const size_t NX = (size_t)4 * 4096 * 256;       // 4,194,304 elements
    float* ws   = (float*)d_ws;
    float* x_t  = ws;                               // [4][4096][256] fp32 (dead after conv_x)
    float* z_t  = ws + NX;                          // [4][4096][256] fp32
    float* u_t  = ws + 2 * NX;                      // [4][4096][256] fp32
    float* dlt  = ws + 3 * NX;                      // [4][4096][256] fp32
    float* xdbl = ws + 4 * NX;                      // [4][4096][48]
    float* chS  = xdbl + 786432;                    // [4][256][256]
    float* chB  = chS + 262144;                     // [4][256][8][256]
    float* hin  = chB + 2097152;                    // [4][256][8][256]
    float* wtT  = hin + 2097152;                    // [32][256] Wdt^T
    _Float16* hsf = (_Float16*)(wtT + 8192);        // [8192][512] fp16
    _Float16* wif = hsf + 4194304;                  // [1024][512] fp16
    _Float16* wof = wif + 524288;                   // [512][1024] fp16
    // alias (stream order makes this safe): ybuf fp16 over dead x_t (exact fit)
    _Float16* ybf = (_Float16*)x_t;                 // [2][4096][1024] fp16

    k_cast_all     <<<5152,  256, 0, stream>>>(hs, hsf, w_in, wif, w_out, wof, w_dt, wtT);
    k_in_proj_mfma <<<1024,  256, 0, stream>>>(hsf, wif, x_t, z_t);
    k_conv_x4      <<<4096,  256, 0, stream>>>(x_t, w_cx, u_t);
    k_conv_z4      <<<4096,  256, 0, stream>>>(z_t, w_cz, ybf);
    k_xproj        <<<512,   256, 0, stream>>>(u_t, w_xp, xdbl);
    k_dtproj       <<<1024,  256, 0, stream>>>(xdbl, wtT, b_dt, dlt);
    k_scan1        <<<1024,  256, 0, stream>>>(dlt, u_t, xdbl, A_log, chS, chB);
    k_scan2        <<<32,    256, 0, stream>>>(chS, chB, A_log, hin);
    k_scan3        <<<1024,  256, 0, stream>>>(dlt, u_t, xdbl, A_log, Dpar, hin, ybf);
    k_out_proj_mfma<<<512,   256, 0, stream>>>(ybf, wof, out);
}